// Round 8
// baseline (2861.303 us; speedup 1.0000x reference)
//
#include <hip/hip_runtime.h>
#include <hip/hip_bf16.h>
#include <math.h>

#define D_DIM 1024
#define T_DIM 2048
#define B_DIM 8
#define M_DIM (B_DIM * T_DIM)          // 16384
#define SZ ((size_t)M_DIM * D_DIM)     // 16777216
#define NW 11
#define CCH 16                          // scan chunks
#define LCH 128                         // scan chunk length

typedef __bf16 bf16_t;
typedef __bf16 bf16x8 __attribute__((ext_vector_type(8)));
typedef __bf16 bf16x4 __attribute__((ext_vector_type(4)));
typedef float f32x4 __attribute__((ext_vector_type(4)));

typedef const __attribute__((address_space(1))) void* as1_const_ptr;
typedef __attribute__((address_space(3))) void* as3_ptr;

__device__ __forceinline__ void load_lds_16(const void* g, void* l) {
    __builtin_amdgcn_global_load_lds((as1_const_ptr)g, (as3_ptr)l, 16, 0, 0);
}

__device__ __forceinline__ float sigmoid_f(float x) { return 1.f / (1.f + expf(-x)); }

// ---------------------------------------------------------------------------
// GEMM v5 (r6-verified): 256x128 tile, BK=32, 512 thr (8 waves 4x2; per-wave
// 64x64 out via 4x4 mfma 16x16x32). 2-phase double-buffered K-loop, chunk
// XOR-swizzle (chunk ^= (row>>1)&3) on global source + fragment read.
// __launch_bounds__(512,4); XCD swizzle: xcd = lin&7.
//
// MODE epilogues:
//  3: out0 fp32 = acc + other_f32  (residual; may alias)  (Wout, Wffnout)
//  7: h = acc + bias0 -> out0 fp32, PLUS grn partial: out1[mt*D + col] =
//     sum over the block's 256 rows of h^2 (quad-shfl + LDS wave reduce).
// ---------------------------------------------------------------------------
template<int NT, int MODE>
__global__ void __launch_bounds__(512, 4)
gemm2_kernel(const bf16_t* __restrict__ A, const bf16_t* __restrict__ Bt,
             void* __restrict__ out0, void* __restrict__ out1,
             const float* __restrict__ bias0, const float* __restrict__ bias1,
             const void* __restrict__ other)
{
    constexpr int K = D_DIM;
    __shared__ bf16_t sA[2][256 * 32];      // 32 KB
    __shared__ bf16_t sB[2][128 * 32];      // 16 KB
    __shared__ float gsum[8][64];           // 2 KB (MODE 7 reduce)
    const int tid  = threadIdx.x;
    const int wave = tid >> 6, lane = tid & 63;

    const int lin = blockIdx.x;
    const int xcd = lin & 7;
    const int idx = lin >> 3;               // 0 .. 8*NT-1
    const int mt  = xcd * 8 + idx / NT;     // 0..63
    const int nt  = idx % NT;
    const int m0 = mt * 256, n0 = nt * 128;

    const int wm = (wave & 3) * 64;         // 0..192
    const int wn = (wave >> 2) * 64;        // 0 / 64

    const int rl = lane >> 2;
    const int cc = lane & 3;
    const int scol = (cc ^ ((rl >> 1) & 3)) * 8;
    const bf16_t* gA = A  + (size_t)(m0 + wave * 32 + rl) * K + scol;
    const bf16_t* gB = Bt + (size_t)(n0 + wave * 16 + rl) * K + scol;
    const int lofsA = (wave * 32) * 32;
    const int lofsB = (wave * 16) * 32;

    f32x4 acc[4][4] = {};

    const int fr = lane & 15;
    const int quad = lane >> 4;
    const int qs = (quad ^ ((fr >> 1) & 3)) * 8;   // swizzled fragment chunk

    load_lds_16(gA,                   &sA[0][lofsA]);
    load_lds_16(gA + (size_t)16 * K,  &sA[0][lofsA + 16 * 32]);
    load_lds_16(gB,                   &sB[0][lofsB]);
    __syncthreads();

    int cur = 0;
    for (int kk = 0; kk < K; kk += 32) {
        if (kk + 32 < K) {
            const int nb = cur ^ 1;
            load_lds_16(gA + kk + 32,                   &sA[nb][lofsA]);
            load_lds_16(gA + (size_t)16 * K + kk + 32,  &sA[nb][lofsA + 16 * 32]);
            load_lds_16(gB + kk + 32,                   &sB[nb][lofsB]);
        }
        bf16x8 af[4], bq[4];
        #pragma unroll
        for (int i = 0; i < 4; i++)
            af[i] = *(const bf16x8*)(&sA[cur][(wm + i * 16 + fr) * 32 + qs]);
        #pragma unroll
        for (int j = 0; j < 4; j++)
            bq[j] = *(const bf16x8*)(&sB[cur][(wn + j * 16 + fr) * 32 + qs]);
        #pragma unroll
        for (int i = 0; i < 4; i++)
            #pragma unroll
            for (int j = 0; j < 4; j++)
                acc[i][j] = __builtin_amdgcn_mfma_f32_16x16x32_bf16(af[i], bq[j], acc[i][j], 0, 0, 0);
        __syncthreads();
        cur ^= 1;
    }

    float hs[4] = {0.f, 0.f, 0.f, 0.f};     // MODE 7 per-col h^2 partials

    #pragma unroll
    for (int i = 0; i < 4; i++) {
        #pragma unroll
        for (int j = 0; j < 4; j++) {
            const int col = n0 + wn + j * 16 + fr;
            #pragma unroll
            for (int r = 0; r < 4; r++) {
                const int row = m0 + wm + i * 16 + quad * 4 + r;
                float v = acc[i][j][r];
                if constexpr (MODE == 3) {
                    const size_t id = (size_t)row * D_DIM + col;
                    ((float*)out0)[id] = v + ((const float*)other)[id];
                } else {                                    // MODE 7: h + grn
                    const float h = v + bias0[col];
                    ((float*)out0)[(size_t)row * D_DIM + col] = h;
                    hs[j] += h * h;
                }
            }
        }
    }

    if constexpr (MODE == 7) {
        #pragma unroll
        for (int j = 0; j < 4; j++) {
            float t = hs[j];
            t += __shfl_xor(t, 16);
            t += __shfl_xor(t, 32);
            if (lane < 16) gsum[wave][j * 16 + fr] = t;
        }
        __syncthreads();
        if (tid < 128) {
            const int p = tid >> 6, jf = tid & 63;   // p = wn half
            const float tot = gsum[4 * p + 0][jf] + gsum[4 * p + 1][jf]
                            + gsum[4 * p + 2][jf] + gsum[4 * p + 3][jf];
            ((float*)out1)[(size_t)mt * D_DIM + n0 + p * 64 + jf] = tot;
        }
    }
}

// ---------------------------------------------------------------------------
// PAIR GEMM: 256x128 tile, A staged once + TWO B panels per K-step (4 panels
// per 4 MFMA-units = 1.0 staged-panel/unit vs gemm2's 1.5). 64 KB LDS
// (2 blocks/CU), 32 MFMA per barrier. Staging/fragment geometry identical to
// the r6-verified gemm2; second B panel staged identically into sB2.
//
// MODE 0 (r,g):   out0 = sigmoid(acc1) bf16, out1 = sigmoid(acc2) bf16
// MODE 1 (ffn):   out0 = relu^2(acc1+bias0) bf16, out1 = sigmoid(acc2+bias1)
// ---------------------------------------------------------------------------
template<int MODE>
__global__ void __launch_bounds__(512, 4)
gemm_pair_kernel(const bf16_t* __restrict__ A, const bf16_t* __restrict__ B1t,
                 const bf16_t* __restrict__ B2t,
                 void* __restrict__ out0, void* __restrict__ out1,
                 const float* __restrict__ bias0, const float* __restrict__ bias1)
{
    constexpr int K = D_DIM;
    __shared__ bf16_t sA[2][256 * 32];      // 32 KB
    __shared__ bf16_t sB1[2][128 * 32];     // 16 KB
    __shared__ bf16_t sB2[2][128 * 32];     // 16 KB
    const int tid  = threadIdx.x;
    const int wave = tid >> 6, lane = tid & 63;

    const int lin = blockIdx.x;             // grid = 512 (64 mt x 8 nt)
    const int xcd = lin & 7;
    const int idx = lin >> 3;               // 0..63
    const int mt  = xcd * 8 + (idx >> 3);   // 0..63
    const int nt  = idx & 7;
    const int m0 = mt * 256, n0 = nt * 128;

    const int wm = (wave & 3) * 64;
    const int wn = (wave >> 2) * 64;

    const int rl = lane >> 2;
    const int cc = lane & 3;
    const int scol = (cc ^ ((rl >> 1) & 3)) * 8;
    const bf16_t* gA  = A   + (size_t)(m0 + wave * 32 + rl) * K + scol;
    const bf16_t* gB1 = B1t + (size_t)(n0 + wave * 16 + rl) * K + scol;
    const bf16_t* gB2 = B2t + (size_t)(n0 + wave * 16 + rl) * K + scol;
    const int lofsA = (wave * 32) * 32;
    const int lofsB = (wave * 16) * 32;

    f32x4 acc1[4][4] = {}, acc2[4][4] = {};

    const int fr = lane & 15;
    const int quad = lane >> 4;
    const int qs = (quad ^ ((fr >> 1) & 3)) * 8;

    load_lds_16(gA,                   &sA[0][lofsA]);
    load_lds_16(gA + (size_t)16 * K,  &sA[0][lofsA + 16 * 32]);
    load_lds_16(gB1,                  &sB1[0][lofsB]);
    load_lds_16(gB2,                  &sB2[0][lofsB]);
    __syncthreads();

    int cur = 0;
    for (int kk = 0; kk < K; kk += 32) {
        if (kk + 32 < K) {
            const int nb = cur ^ 1;
            load_lds_16(gA + kk + 32,                   &sA[nb][lofsA]);
            load_lds_16(gA + (size_t)16 * K + kk + 32,  &sA[nb][lofsA + 16 * 32]);
            load_lds_16(gB1 + kk + 32,                  &sB1[nb][lofsB]);
            load_lds_16(gB2 + kk + 32,                  &sB2[nb][lofsB]);
        }
        bf16x8 af[4], b1[4], b2[4];
        #pragma unroll
        for (int i = 0; i < 4; i++)
            af[i] = *(const bf16x8*)(&sA[cur][(wm + i * 16 + fr) * 32 + qs]);
        #pragma unroll
        for (int j = 0; j < 4; j++) {
            b1[j] = *(const bf16x8*)(&sB1[cur][(wn + j * 16 + fr) * 32 + qs]);
            b2[j] = *(const bf16x8*)(&sB2[cur][(wn + j * 16 + fr) * 32 + qs]);
        }
        #pragma unroll
        for (int i = 0; i < 4; i++)
            #pragma unroll
            for (int j = 0; j < 4; j++) {
                acc1[i][j] = __builtin_amdgcn_mfma_f32_16x16x32_bf16(af[i], b1[j], acc1[i][j], 0, 0, 0);
                acc2[i][j] = __builtin_amdgcn_mfma_f32_16x16x32_bf16(af[i], b2[j], acc2[i][j], 0, 0, 0);
            }
        __syncthreads();
        cur ^= 1;
    }

    #pragma unroll
    for (int i = 0; i < 4; i++) {
        #pragma unroll
        for (int j = 0; j < 4; j++) {
            const int col = n0 + wn + j * 16 + fr;
            #pragma unroll
            for (int r = 0; r < 4; r++) {
                const int row = m0 + wm + i * 16 + quad * 4 + r;
                const size_t id = (size_t)row * D_DIM + col;
                const float v1 = acc1[i][j][r];
                const float v2 = acc2[i][j][r];
                if constexpr (MODE == 0) {          // r, g
                    ((bf16_t*)out0)[id] = (bf16_t)sigmoid_f(v1);
                    ((bf16_t*)out1)[id] = (bf16_t)sigmoid_f(v2);
                } else {                            // k_ffn, fr
                    float t = fmaxf(v1 + bias0[col], 0.f);
                    ((bf16_t*)out0)[id] = (bf16_t)(t * t);
                    ((bf16_t*)out1)[id] = (bf16_t)sigmoid_f(v2 + bias1[col]);
                }
            }
        }
    }
}

// ---------------------------------------------------------------------------
// Fused u-kernel v3: 256x128 tile pair-fused, u = (xm@Wk)*(xm@Wv) +
// (xm@Wa)*(xm@Wb). Two passes of the pair loop ({Wk,Wv}, then {Wa,Wb});
// staging economics 1.0 panel/MFMA-unit (vs r7's 1.5). 64 KB LDS, 512 thr,
// 2 blocks/CU. Pass-2 register peak: 3 acc sets (192 f32) + frags ~ 260 VGPR
// (no-spill range). MFMA K-order per matrix identical to r7 -> same output.
// Wt4 = Wk,Wv,Wa,Wb transposed bf16, contiguous slots.
// ---------------------------------------------------------------------------
__global__ void __launch_bounds__(512, 4)
gemm_uv_kernel(const bf16_t* __restrict__ A, const bf16_t* __restrict__ Wt4,
               float* __restrict__ u)
{
    constexpr int K = D_DIM;
    constexpr size_t WSZ_E = (size_t)D_DIM * D_DIM;
    __shared__ bf16_t sA[2][256 * 32];      // 32 KB
    __shared__ bf16_t sB1[2][128 * 32];     // 16 KB
    __shared__ bf16_t sB2[2][128 * 32];     // 16 KB
    const int tid  = threadIdx.x;
    const int wave = tid >> 6, lane = tid & 63;

    const int lin = blockIdx.x;             // grid = 512 (64 mt x 8 nt)
    const int xcd = lin & 7;
    const int idx = lin >> 3;
    const int mt  = xcd * 8 + (idx >> 3);
    const int nt  = idx & 7;
    const int m0 = mt * 256, n0 = nt * 128;

    const int wm = (wave & 3) * 64;
    const int wn = (wave >> 2) * 64;

    const int rl = lane >> 2;
    const int cc = lane & 3;
    const int scol = (cc ^ ((rl >> 1) & 3)) * 8;
    const bf16_t* gA  = A   + (size_t)(m0 + wave * 32 + rl) * K + scol;
    const bf16_t* gB0 = Wt4 + (size_t)(n0 + wave * 16 + rl) * K + scol;
    const int lofsA = (wave * 32) * 32;
    const int lofsB = (wave * 16) * 32;

    const int fr = lane & 15;
    const int quad = lane >> 4;
    const int qs = (quad ^ ((fr >> 1) & 3)) * 8;

    // one pass: acc1 += A@B1, acc2 += A@B2; A staged once per K-step
    auto kloop2 = [&](const bf16_t* gB1, const bf16_t* gB2,
                      f32x4 (&acc1)[4][4], f32x4 (&acc2)[4][4]) {
        load_lds_16(gA,                   &sA[0][lofsA]);
        load_lds_16(gA + (size_t)16 * K,  &sA[0][lofsA + 16 * 32]);
        load_lds_16(gB1,                  &sB1[0][lofsB]);
        load_lds_16(gB2,                  &sB2[0][lofsB]);
        __syncthreads();
        int cur = 0;
        for (int kk = 0; kk < K; kk += 32) {
            if (kk + 32 < K) {
                const int nb = cur ^ 1;
                load_lds_16(gA + kk + 32,                   &sA[nb][lofsA]);
                load_lds_16(gA + (size_t)16 * K + kk + 32,  &sA[nb][lofsA + 16 * 32]);
                load_lds_16(gB1 + kk + 32,                  &sB1[nb][lofsB]);
                load_lds_16(gB2 + kk + 32,                  &sB2[nb][lofsB]);
            }
            bf16x8 af[4], b1[4], b2[4];
            #pragma unroll
            for (int i = 0; i < 4; i++)
                af[i] = *(const bf16x8*)(&sA[cur][(wm + i * 16 + fr) * 32 + qs]);
            #pragma unroll
            for (int j = 0; j < 4; j++) {
                b1[j] = *(const bf16x8*)(&sB1[cur][(wn + j * 16 + fr) * 32 + qs]);
                b2[j] = *(const bf16x8*)(&sB2[cur][(wn + j * 16 + fr) * 32 + qs]);
            }
            #pragma unroll
            for (int i = 0; i < 4; i++)
                #pragma unroll
                for (int j = 0; j < 4; j++) {
                    acc1[i][j] = __builtin_amdgcn_mfma_f32_16x16x32_bf16(af[i], b1[j], acc1[i][j], 0, 0, 0);
                    acc2[i][j] = __builtin_amdgcn_mfma_f32_16x16x32_bf16(af[i], b2[j], acc2[i][j], 0, 0, 0);
                }
            __syncthreads();
            cur ^= 1;
        }
    };

    f32x4 aKV[4][4] = {};   // k, then k*v
    f32x4 aT[4][4]  = {};   // v, then a
    f32x4 aB2[4][4] = {};   // b

    kloop2(gB0, gB0 + WSZ_E, aKV, aT);          // k, v
    #pragma unroll
    for (int i = 0; i < 4; i++)
        #pragma unroll
        for (int j = 0; j < 4; j++) {
            aKV[i][j] = aKV[i][j] * aT[i][j];
            aT[i][j] = f32x4{0.f, 0.f, 0.f, 0.f};
        }
    kloop2(gB0 + 2 * WSZ_E, gB0 + 3 * WSZ_E, aT, aB2);   // a, b

    #pragma unroll
    for (int i = 0; i < 4; i++) {
        #pragma unroll
        for (int j = 0; j < 4; j++) {
            const int col = n0 + wn + j * 16 + fr;
            #pragma unroll
            for (int r = 0; r < 4; r++) {
                const int row = m0 + wm + i * 16 + quad * 4 + r;
                u[(size_t)row * D_DIM + col] =
                    aKV[i][j][r] + aT[i][j][r] * aB2[i][j][r];
            }
        }
    }
}

// ---------------------------------------------------------------------------
// Weight transpose + fp32->bf16:  Wt[n][k] = W[k][n]
// ---------------------------------------------------------------------------
struct WList { const float* w[NW]; };

__global__ void __launch_bounds__(256)
transpose_cvt_kernel(WList wl, bf16_t* wt_base)
{
    __shared__ float tile[32][33];
    const float* W = wl.w[blockIdx.z];
    bf16_t* Wt = wt_base + (size_t)blockIdx.z * D_DIM * D_DIM;
    const int bx = blockIdx.x * 32, by = blockIdx.y * 32;
    const int tx = threadIdx.x, ty = threadIdx.y;
    #pragma unroll
    for (int i = 0; i < 32; i += 8)
        tile[ty + i][tx] = W[(size_t)(by + ty + i) * D_DIM + bx + tx];
    __syncthreads();
    #pragma unroll
    for (int i = 0; i < 32; i += 8)
        Wt[(size_t)(bx + ty + i) * D_DIM + by + tx] = (bf16_t)tile[tx][ty + i];
}

// ---------------------------------------------------------------------------
// ew[d] = exp(decay[d])
// ---------------------------------------------------------------------------
__global__ void __launch_bounds__(256)
ew_kernel(const float* __restrict__ decay, float* __restrict__ ew)
{
    const int d = blockIdx.x * 256 + threadIdx.x;
    if (d < D_DIM) ew[d] = expf(decay[d]);
}

// ---------------------------------------------------------------------------
// LN1 of rows t and t-1, xm = 0.5*(xx_t + xx_{t-1}) -> bf16. One block per row.
// ---------------------------------------------------------------------------
__global__ void __launch_bounds__(256)
ln_shift_kernel(const float* __restrict__ x, const float* __restrict__ w,
                const float* __restrict__ bias, bf16_t* __restrict__ xm)
{
    const int row = blockIdx.x;
    const int t = row & (T_DIM - 1);
    const int d0 = threadIdx.x * 4;
    const float* xc = x + (size_t)row * D_DIM;
    f32x4 c = *(const f32x4*)(xc + d0);
    f32x4 p = {0.f, 0.f, 0.f, 0.f};
    if (t > 0) p = *(const f32x4*)(xc - D_DIM + d0);

    float sc = 0.f, qc = 0.f, sp = 0.f, qp = 0.f;
    #pragma unroll
    for (int e = 0; e < 4; e++) {
        sc += c[e]; qc += c[e] * c[e];
        sp += p[e]; qp += p[e] * p[e];
    }
    #pragma unroll
    for (int off = 32; off > 0; off >>= 1) {
        sc += __shfl_down(sc, off); qc += __shfl_down(qc, off);
        sp += __shfl_down(sp, off); qp += __shfl_down(qp, off);
    }
    __shared__ float red[16];
    const int wv = threadIdx.x >> 6, ln = threadIdx.x & 63;
    if (ln == 0) { red[wv] = sc; red[4 + wv] = qc; red[8 + wv] = sp; red[12 + wv] = qp; }
    __syncthreads();
    sc = red[0] + red[1] + red[2] + red[3];
    qc = red[4] + red[5] + red[6] + red[7];
    sp = red[8] + red[9] + red[10] + red[11];
    qp = red[12] + red[13] + red[14] + red[15];

    const float inv = 1.f / (float)D_DIM;
    const float mc = sc * inv, vc = qc * inv - mc * mc, rc = rsqrtf(vc + 1e-5f);
    const float mp = sp * inv, vp = qp * inv - mp * mp, rp = rsqrtf(vp + 1e-5f);

    bf16x4 o;
    #pragma unroll
    for (int e = 0; e < 4; e++) {
        const int d = d0 + e;
        const float wd = w[d], bd = bias[d];
        const float nc = (c[e] - mc) * rc * wd + bd;
        const float np = (t > 0) ? ((p[e] - mp) * rp * wd + bd) : 0.f;
        o[e] = (bf16_t)(0.5f * (nc + np));
    }
    *(bf16x4*)(xm + (size_t)row * D_DIM + d0) = o;
}

// ---------------------------------------------------------------------------
// scan pass 1: local chunk scans (zero init), IN-PLACE u -> states, + carry out
// ---------------------------------------------------------------------------
__global__ void __launch_bounds__(256)
scan1_kernel(float* __restrict__ u, const float* __restrict__ ew,
             float* __restrict__ carry)
{
    const int gid = blockIdx.x * 256 + threadIdx.x;   // (c*B + b)*D + d
    const int d = gid & (D_DIM - 1);
    const int b = (gid >> 10) & (B_DIM - 1);
    const int c = gid >> 13;
    const float w = expf(-ew[d]);
    float s = 0.f;
    const size_t base = ((size_t)b * T_DIM + (size_t)c * LCH) * D_DIM + d;
    #pragma unroll 4
    for (int tl = 0; tl < LCH; tl++) {
        const size_t idx = base + (size_t)tl * D_DIM;
        s = fmaf(s, w, u[idx]);
        u[idx] = s;
    }
    carry[(size_t)(b * CCH + c) * D_DIM + d] = s;
}

// ---------------------------------------------------------------------------
// scan pass 2: combine carries sequentially -> incoming per chunk + final state
// ---------------------------------------------------------------------------
__global__ void __launch_bounds__(256)
scan2_kernel(const float* __restrict__ s0, const float* __restrict__ ew,
             const float* __restrict__ carry, float* __restrict__ inc,
             float* __restrict__ fstate)
{
    const int gid = blockIdx.x * 256 + threadIdx.x;   // b*D + d
    const int d = gid & (D_DIM - 1);
    const int b = gid >> 10;
    const float wL = expf(-(float)LCH * ew[d]);
    float s = s0[gid];
    #pragma unroll
    for (int c = 0; c < CCH; c++) {
        const size_t idx = (size_t)(b * CCH + c) * D_DIM + d;
        inc[idx] = s;
        s = fmaf(s, wL, carry[idx]);
    }
    fstate[gid] = s;
}

// ---------------------------------------------------------------------------
// scan recombine + GroupNorm(32ch) + mixed = sr*ns*g -> bf16
// ---------------------------------------------------------------------------
__global__ void __launch_bounds__(256)
mixed_kernel(const float* __restrict__ st, const float* __restrict__ inc,
             const float* __restrict__ ew, const bf16_t* __restrict__ sr,
             const bf16_t* __restrict__ g, const float* __restrict__ gnw,
             const float* __restrict__ gnb, bf16_t* __restrict__ outp)
{
    const int row = blockIdx.x;                 // b*T + t
    const int b = row >> 11;
    const int t = row & (T_DIM - 1);
    const int c = t >> 7, tl = t & (LCH - 1);
    const int d0 = threadIdx.x * 4;
    const size_t base = (size_t)row * D_DIM + d0;

    f32x4 lv = *(const f32x4*)(st + base);
    f32x4 iv = *(const f32x4*)(inc + (size_t)(b * CCH + c) * D_DIM + d0);
    f32x4 ev = *(const f32x4*)(ew + d0);

    float s[4];
    float sum = 0.f, sq = 0.f;
    #pragma unroll
    for (int e = 0; e < 4; e++) {
        s[e] = lv[e] + expf(-(float)(tl + 1) * ev[e]) * iv[e];
        sum += s[e]; sq += s[e] * s[e];
    }
    // group of 32 channels == 8 consecutive lanes
    #pragma unroll
    for (int m = 1; m <= 4; m <<= 1) { sum += __shfl_xor(sum, m); sq += __shfl_xor(sq, m); }
    const float mean = sum * (1.f / 32.f);
    const float var  = sq * (1.f / 32.f) - mean * mean;
    const float rstd = rsqrtf(var + 1e-5f);

    bf16x4 rv = *(const bf16x4*)(sr + base);
    bf16x4 gv = *(const bf16x4*)(g + base);
    f32x4 wv = *(const f32x4*)(gnw + d0);
    f32x4 bv = *(const f32x4*)(gnb + d0);
    bf16x4 o;
    #pragma unroll
    for (int e = 0; e < 4; e++) {
        const float ns = (s[e] - mean) * rstd * wv[e] + bv[e];
        o[e] = (bf16_t)((float)rv[e] * ns * (float)gv[e]);
    }
    *(bf16x4*)(outp + base) = o;
}

// ---------------------------------------------------------------------------
// LN2: read x2, write normalized bf16
// ---------------------------------------------------------------------------
__global__ void __launch_bounds__(256)
ln2_kernel(const float* __restrict__ x2, const float* __restrict__ w,
           const float* __restrict__ bias, bf16_t* __restrict__ xx2)
{
    const int row = blockIdx.x;
    const int d0 = threadIdx.x * 4;
    const float* xc = x2 + (size_t)row * D_DIM;
    f32x4 c = *(const f32x4*)(xc + d0);
    float sc = 0.f, qc = 0.f;
    #pragma unroll
    for (int e = 0; e < 4; e++) { sc += c[e]; qc += c[e] * c[e]; }
    #pragma unroll
    for (int off = 32; off > 0; off >>= 1) {
        sc += __shfl_down(sc, off); qc += __shfl_down(qc, off);
    }
    __shared__ float red[8];
    const int wv = threadIdx.x >> 6, ln = threadIdx.x & 63;
    if (ln == 0) { red[wv] = sc; red[4 + wv] = qc; }
    __syncthreads();
    sc = red[0] + red[1] + red[2] + red[3];
    qc = red[4] + red[5] + red[6] + red[7];
    const float inv = 1.f / (float)D_DIM;
    const float m = sc * inv, v = qc * inv - m * m, rs = rsqrtf(v + 1e-5f);
    bf16x4 o;
    #pragma unroll
    for (int e = 0; e < 4; e++) {
        const int d = d0 + e;
        o[e] = (bf16_t)((c[e] - m) * rs * w[d] + bias[d]);
    }
    *(bf16x4*)(xx2 + (size_t)row * D_DIM + d0) = o;
}

// ---------------------------------------------------------------------------
// GRN pass 2: gx = sqrt(sum over 8 m-tile partials), nx = gx/(mean_d(gx)+1e-6)
// ---------------------------------------------------------------------------
__global__ void __launch_bounds__(1024)
grn2_kernel(const float* __restrict__ partial, float* __restrict__ nx)
{
    const int b = blockIdx.x, d = threadIdx.x;
    float s = 0.f;
    #pragma unroll
    for (int c = 0; c < 8; c++) s += partial[(size_t)(b * 8 + c) * D_DIM + d];
    const float gx = sqrtf(s);
    float v = gx;
    #pragma unroll
    for (int off = 32; off > 0; off >>= 1) v += __shfl_down(v, off);
    __shared__ float red[16];
    if ((threadIdx.x & 63) == 0) red[threadIdx.x >> 6] = v;
    __syncthreads();
    float tot = 0.f;
    #pragma unroll
    for (int i = 0; i < 16; i++) tot += red[i];
    nx[b * D_DIM + d] = gx / (tot * (1.f / (float)D_DIM) + 1e-6f);
}

// ---------------------------------------------------------------------------
// frh = fr * (gamma*(h*nx) + beta + h) -> bf16
// ---------------------------------------------------------------------------
__global__ void __launch_bounds__(256)
frh_kernel(const float* __restrict__ h, const bf16_t* __restrict__ fr,
           const float* __restrict__ nx, const float* __restrict__ gamma,
           const float* __restrict__ beta, bf16_t* __restrict__ outp)
{
    const size_t gid = (size_t)blockIdx.x * 256 + threadIdx.x;
    const size_t i4 = gid * 4;
    const int d = (int)(i4 & (D_DIM - 1));
    const int b = (int)(i4 >> 21);     // T*D = 2^21
    f32x4 hv = *(const f32x4*)(h + i4);
    bf16x4 fv = *(const bf16x4*)(fr + i4);
    f32x4 nv = *(const f32x4*)(nx + (size_t)b * D_DIM + d);
    f32x4 gm = *(const f32x4*)(gamma + d);
    f32x4 bt = *(const f32x4*)(beta + d);
    bf16x4 o;
    #pragma unroll
    for (int e = 0; e < 4; e++) {
        const float hh = hv[e];
        const float val = gm[e] * (hh * nv[e]) + bt[e] + hh;
        o[e] = (bf16_t)((float)fv[e] * val);
    }
    *(bf16x4*)(outp + i4) = o;
}

// ---------------------------------------------------------------------------
extern "C" void kernel_launch(void* const* d_in, const int* in_sizes, int n_in,
                              void* d_out, int out_size, void* d_ws, size_t ws_size,
                              hipStream_t stream)
{
    (void)in_sizes; (void)n_in; (void)out_size; (void)ws_size;

    const float* x      = (const float*)d_in[0];
    const float* state0 = (const float*)d_in[1];
    const float* ln1_w  = (const float*)d_in[2];
    const float* ln1_b  = (const float*)d_in[3];
    const float* ln2_w  = (const float*)d_in[4];
    const float* ln2_b  = (const float*)d_in[5];
    const float* gn_w   = (const float*)d_in[6];
    const float* gn_b   = (const float*)d_in[7];
    const float* grn_g  = (const float*)d_in[8];
    const float* grn_b  = (const float*)d_in[9];
    const float* decay  = (const float*)d_in[10];
    const float* bfk    = (const float*)d_in[20];
    const float* bfv    = (const float*)d_in[22];
    const float* bfr    = (const float*)d_in[24];

    // workspace layout (~223 MB total)
    const size_t WSZ = (size_t)D_DIM * D_DIM;
    float*  F1 = (float*)d_ws;         // u -> states -> h        (fp32, 64MB)
    bf16_t* B0 = (bf16_t*)(F1 + SZ);   // xm -> xx2               (bf16, 32MB)
    bf16_t* B1 = B0 + SZ;              // mixed -> k_ffn
    bf16_t* B2 = B1 + SZ;              // sr=sigmoid(r) -> fr
    bf16_t* B3 = B2 + SZ;              // g -> frh
    bf16_t* WT = B3 + SZ;              // 11 transposed bf16 weights (22MB)
    float*  carry   = (float*)(WT + NW * WSZ);
    float*  inc     = carry + (size_t)B_DIM * CCH * D_DIM;
    float*  partial = inc + (size_t)B_DIM * CCH * D_DIM;   // 64 x D grn partials
    float*  nxp     = partial + (size_t)64 * D_DIM;
    float*  ewp     = nxp + (size_t)B_DIM * D_DIM;

    // weight slots (fusion-contiguous):
    // 0 Wr, 1 Wg (pair proj), 2 Wk, 3 Wv, 4 Wa, 5 Wb (uv),
    // 6 Wout, 7 Wfk, 8 Wfr (pair ffn), 9 Wfv, 10 Wffnout
    WList wl;
    const int widx[NW] = {11, 14, 12, 13, 15, 16, 17, 19, 23, 21, 18};
    for (int i = 0; i < NW; i++) wl.w[i] = (const float*)d_in[widx[i]];

    float* out_x  = (float*)d_out;
    float* out_st = out_x + SZ;

    transpose_cvt_kernel<<<dim3(32, 32, NW), dim3(32, 8), 0, stream>>>(wl, WT);
    ew_kernel<<<4, 256, 0, stream>>>(decay, ewp);
    ln_shift_kernel<<<M_DIM, 256, 0, stream>>>(x, ln1_w, ln1_b, B0);

    // pair proj: sr=sigmoid(xm@Wr)->B2, g=sigmoid(xm@Wg)->B3
    gemm_pair_kernel<0><<<512, 512, 0, stream>>>(
        B0, WT + 0 * WSZ, WT + 1 * WSZ, B2, B3, nullptr, nullptr);
    // u = (xm@Wk)*(xm@Wv) + (xm@Wa)*(xm@Wb)  -> F1 (single write)
    gemm_uv_kernel<<<512, 512, 0, stream>>>(B0, WT + 2 * WSZ, F1);

    scan1_kernel<<<(CCH * B_DIM * D_DIM) / 256, 256, 0, stream>>>(F1, ewp, carry);
    scan2_kernel<<<(B_DIM * D_DIM) / 256, 256, 0, stream>>>(state0, ewp, carry, inc, out_st);
    mixed_kernel<<<M_DIM, 256, 0, stream>>>(F1, inc, ewp, B2, B3, gn_w, gn_b, B1);

    // x2 = x + mixed @ Wout  -> directly into d_out
    gemm2_kernel<8, 3><<<512, 512, 0, stream>>>(
        B1, WT + 6 * WSZ, out_x, nullptr, nullptr, nullptr, x);
    ln2_kernel<<<M_DIM, 256, 0, stream>>>(out_x, ln2_w, ln2_b, B0);

    // pair ffn: k_ffn = relu^2(xx2@Wfk + bfk)->B1, fr = sigmoid(xx2@Wfr + bfr)->B2
    gemm_pair_kernel<1><<<512, 512, 0, stream>>>(
        B0, WT + 7 * WSZ, WT + 8 * WSZ, B1, B2, bfk, bfr);
    // h = k_ffn @ Wfv + bfv -> F1, plus grn h^2 partials -> partial (MODE 7)
    gemm2_kernel<8, 7><<<512, 512, 0, stream>>>(
        B1, WT + 9 * WSZ, F1, partial, bfv, nullptr, nullptr);

    grn2_kernel<<<B_DIM, 1024, 0, stream>>>(partial, nxp);
    frh_kernel<<<M_DIM, 256, 0, stream>>>(F1, B2, nxp, grn_g, grn_b, B3);

    // out = x2 + frh @ Wffnout  (in-place accumulate into d_out)
    gemm2_kernel<8, 3><<<512, 512, 0, stream>>>(
        B3, WT + 10 * WSZ, out_x, nullptr, nullptr, nullptr, out_x);
}

// Round 9
// 850.338 us; speedup vs baseline: 3.3649x; 3.3649x over previous
//
#include <hip/hip_runtime.h>
#include <hip/hip_bf16.h>
#include <math.h>

#define D_DIM 1024
#define T_DIM 2048
#define B_DIM 8
#define M_DIM (B_DIM * T_DIM)          // 16384
#define SZ ((size_t)M_DIM * D_DIM)     // 16777216
#define NW 11
#define CCH 16                          // scan chunks
#define LCH 128                         // scan chunk length

typedef __bf16 bf16_t;
typedef __bf16 bf16x8 __attribute__((ext_vector_type(8)));
typedef __bf16 bf16x4 __attribute__((ext_vector_type(4)));
typedef float f32x4 __attribute__((ext_vector_type(4)));

typedef const __attribute__((address_space(1))) void* as1_const_ptr;
typedef __attribute__((address_space(3))) void* as3_ptr;

__device__ __forceinline__ void load_lds_16(const void* g, void* l) {
    __builtin_amdgcn_global_load_lds((as1_const_ptr)g, (as3_ptr)l, 16, 0, 0);
}

__device__ __forceinline__ float sigmoid_f(float x) { return 1.f / (1.f + expf(-x)); }

// ---------------------------------------------------------------------------
// GEMM v5 (r6-verified): 256x128 tile, BK=32, 512 thr (8 waves 4x2; per-wave
// 64x64 out via 4x4 mfma 16x16x32). 2-phase double-buffered K-loop, chunk
// XOR-swizzle (chunk ^= (row>>1)&3) on global source + fragment read.
// __launch_bounds__(512,4) [VGPR cap 128 — OK: 1 acc set ~100 live].
// XCD swizzle: xcd = lin&7.
//
// MODE epilogues:
//  3: out0 fp32 = acc + other_f32  (residual; may alias)  (Wout, Wffnout)
//  7: h = acc + bias0 -> out0 fp32, PLUS grn partial: out1[mt*D + col] =
//     sum over the block's 256 rows of h^2 (quad-shfl + LDS wave reduce).
// ---------------------------------------------------------------------------
template<int NT, int MODE>
__global__ void __launch_bounds__(512, 4)
gemm2_kernel(const bf16_t* __restrict__ A, const bf16_t* __restrict__ Bt,
             void* __restrict__ out0, void* __restrict__ out1,
             const float* __restrict__ bias0, const float* __restrict__ bias1,
             const void* __restrict__ other)
{
    constexpr int K = D_DIM;
    __shared__ bf16_t sA[2][256 * 32];      // 32 KB
    __shared__ bf16_t sB[2][128 * 32];      // 16 KB
    __shared__ float gsum[8][64];           // 2 KB (MODE 7 reduce)
    const int tid  = threadIdx.x;
    const int wave = tid >> 6, lane = tid & 63;

    const int lin = blockIdx.x;
    const int xcd = lin & 7;
    const int idx = lin >> 3;               // 0 .. 8*NT-1
    const int mt  = xcd * 8 + idx / NT;     // 0..63
    const int nt  = idx % NT;
    const int m0 = mt * 256, n0 = nt * 128;

    const int wm = (wave & 3) * 64;         // 0..192
    const int wn = (wave >> 2) * 64;        // 0 / 64

    const int rl = lane >> 2;
    const int cc = lane & 3;
    const int scol = (cc ^ ((rl >> 1) & 3)) * 8;
    const bf16_t* gA = A  + (size_t)(m0 + wave * 32 + rl) * K + scol;
    const bf16_t* gB = Bt + (size_t)(n0 + wave * 16 + rl) * K + scol;
    const int lofsA = (wave * 32) * 32;
    const int lofsB = (wave * 16) * 32;

    f32x4 acc[4][4] = {};

    const int fr = lane & 15;
    const int quad = lane >> 4;
    const int qs = (quad ^ ((fr >> 1) & 3)) * 8;   // swizzled fragment chunk

    load_lds_16(gA,                   &sA[0][lofsA]);
    load_lds_16(gA + (size_t)16 * K,  &sA[0][lofsA + 16 * 32]);
    load_lds_16(gB,                   &sB[0][lofsB]);
    __syncthreads();

    int cur = 0;
    for (int kk = 0; kk < K; kk += 32) {
        if (kk + 32 < K) {
            const int nb = cur ^ 1;
            load_lds_16(gA + kk + 32,                   &sA[nb][lofsA]);
            load_lds_16(gA + (size_t)16 * K + kk + 32,  &sA[nb][lofsA + 16 * 32]);
            load_lds_16(gB + kk + 32,                   &sB[nb][lofsB]);
        }
        bf16x8 af[4], bq[4];
        #pragma unroll
        for (int i = 0; i < 4; i++)
            af[i] = *(const bf16x8*)(&sA[cur][(wm + i * 16 + fr) * 32 + qs]);
        #pragma unroll
        for (int j = 0; j < 4; j++)
            bq[j] = *(const bf16x8*)(&sB[cur][(wn + j * 16 + fr) * 32 + qs]);
        #pragma unroll
        for (int i = 0; i < 4; i++)
            #pragma unroll
            for (int j = 0; j < 4; j++)
                acc[i][j] = __builtin_amdgcn_mfma_f32_16x16x32_bf16(af[i], bq[j], acc[i][j], 0, 0, 0);
        __syncthreads();
        cur ^= 1;
    }

    float hs[4] = {0.f, 0.f, 0.f, 0.f};     // MODE 7 per-col h^2 partials

    #pragma unroll
    for (int i = 0; i < 4; i++) {
        #pragma unroll
        for (int j = 0; j < 4; j++) {
            const int col = n0 + wn + j * 16 + fr;
            #pragma unroll
            for (int r = 0; r < 4; r++) {
                const int row = m0 + wm + i * 16 + quad * 4 + r;
                float v = acc[i][j][r];
                if constexpr (MODE == 3) {
                    const size_t id = (size_t)row * D_DIM + col;
                    ((float*)out0)[id] = v + ((const float*)other)[id];
                } else {                                    // MODE 7: h + grn
                    const float h = v + bias0[col];
                    ((float*)out0)[(size_t)row * D_DIM + col] = h;
                    hs[j] += h * h;
                }
            }
        }
    }

    if constexpr (MODE == 7) {
        #pragma unroll
        for (int j = 0; j < 4; j++) {
            float t = hs[j];
            t += __shfl_xor(t, 16);
            t += __shfl_xor(t, 32);
            if (lane < 16) gsum[wave][j * 16 + fr] = t;
        }
        __syncthreads();
        if (tid < 128) {
            const int p = tid >> 6, jf = tid & 63;   // p = wn half
            const float tot = gsum[4 * p + 0][jf] + gsum[4 * p + 1][jf]
                            + gsum[4 * p + 2][jf] + gsum[4 * p + 3][jf];
            ((float*)out1)[(size_t)mt * D_DIM + n0 + p * 64 + jf] = tot;
        }
    }
}

// ---------------------------------------------------------------------------
// PAIR GEMM (r7-uv-verified structure): 128x128 tile, A staged once + TWO B
// panels per K-step, 32 MFMA per barrier. 256 thr, __launch_bounds__(256,2)
// [VGPR cap 256 — 2 acc sets (~170 live) fit; r8's (512,4)=128-cap spilled],
// 48 KB LDS, 2 blocks/CU. Exactly r7 gemm_uv's kloop2 + a store epilogue.
//
// MODE 0 (r,g):   out0 = sigmoid(acc1) bf16, out1 = sigmoid(acc2) bf16
// MODE 1 (ffn):   out0 = relu^2(acc1+bias0) bf16, out1 = sigmoid(acc2+bias1)
// ---------------------------------------------------------------------------
template<int MODE>
__global__ void __launch_bounds__(256, 2)
gemm_pair_kernel(const bf16_t* __restrict__ A, const bf16_t* __restrict__ B1t,
                 const bf16_t* __restrict__ B2t,
                 void* __restrict__ out0, void* __restrict__ out1,
                 const float* __restrict__ bias0, const float* __restrict__ bias1)
{
    constexpr int K = D_DIM;
    __shared__ bf16_t sA[2][128 * 32];      // 16 KB
    __shared__ bf16_t sB1[2][128 * 32];     // 16 KB
    __shared__ bf16_t sB2[2][128 * 32];     // 16 KB
    const int tid  = threadIdx.x;
    const int wave = tid >> 6, lane = tid & 63;

    const int lin = blockIdx.x;             // grid = 1024 (8 xcd x 16 mt x 8 nt)
    const int xcd = lin & 7;
    const int idx = lin >> 3;               // 0..127
    const int mt  = xcd * 16 + (idx >> 3);
    const int nt  = idx & 7;
    const int m0 = mt * 128, n0 = nt * 128;

    const int wm = (wave & 1) * 64, wn = (wave >> 1) * 64;

    const int rl = lane >> 2;
    const int cc = lane & 3;
    const int scol = (cc ^ ((rl >> 1) & 3)) * 8;
    const int srow = wave * 32 + rl;
    const bf16_t* gA  = A   + (size_t)(m0 + srow) * K + scol;
    const bf16_t* gB1 = B1t + (size_t)(n0 + srow) * K + scol;
    const bf16_t* gB2 = B2t + (size_t)(n0 + srow) * K + scol;
    const int lofs = (wave * 32) * 32;

    const int fr = lane & 15;
    const int quad = lane >> 4;
    const int qs = (quad ^ ((fr >> 1) & 3)) * 8;

    f32x4 acc1[4][4] = {}, acc2[4][4] = {};

    load_lds_16(gA,                    &sA[0][lofs]);
    load_lds_16(gA  + (size_t)16 * K,  &sA[0][lofs + 16 * 32]);
    load_lds_16(gB1,                   &sB1[0][lofs]);
    load_lds_16(gB1 + (size_t)16 * K,  &sB1[0][lofs + 16 * 32]);
    load_lds_16(gB2,                   &sB2[0][lofs]);
    load_lds_16(gB2 + (size_t)16 * K,  &sB2[0][lofs + 16 * 32]);
    __syncthreads();

    int cur = 0;
    for (int kk = 0; kk < K; kk += 32) {
        if (kk + 32 < K) {
            const int nb = cur ^ 1;
            load_lds_16(gA  + kk + 32,                   &sA[nb][lofs]);
            load_lds_16(gA  + (size_t)16 * K + kk + 32,  &sA[nb][lofs + 16 * 32]);
            load_lds_16(gB1 + kk + 32,                   &sB1[nb][lofs]);
            load_lds_16(gB1 + (size_t)16 * K + kk + 32,  &sB1[nb][lofs + 16 * 32]);
            load_lds_16(gB2 + kk + 32,                   &sB2[nb][lofs]);
            load_lds_16(gB2 + (size_t)16 * K + kk + 32,  &sB2[nb][lofs + 16 * 32]);
        }
        bf16x8 af[4], b1[4], b2[4];
        #pragma unroll
        for (int i = 0; i < 4; i++)
            af[i] = *(const bf16x8*)(&sA[cur][(wm + i * 16 + fr) * 32 + qs]);
        #pragma unroll
        for (int j = 0; j < 4; j++) {
            b1[j] = *(const bf16x8*)(&sB1[cur][(wn + j * 16 + fr) * 32 + qs]);
            b2[j] = *(const bf16x8*)(&sB2[cur][(wn + j * 16 + fr) * 32 + qs]);
        }
        #pragma unroll
        for (int i = 0; i < 4; i++)
            #pragma unroll
            for (int j = 0; j < 4; j++) {
                acc1[i][j] = __builtin_amdgcn_mfma_f32_16x16x32_bf16(af[i], b1[j], acc1[i][j], 0, 0, 0);
                acc2[i][j] = __builtin_amdgcn_mfma_f32_16x16x32_bf16(af[i], b2[j], acc2[i][j], 0, 0, 0);
            }
        __syncthreads();
        cur ^= 1;
    }

    #pragma unroll
    for (int i = 0; i < 4; i++) {
        #pragma unroll
        for (int j = 0; j < 4; j++) {
            const int col = n0 + wn + j * 16 + fr;
            #pragma unroll
            for (int r = 0; r < 4; r++) {
                const int row = m0 + wm + i * 16 + quad * 4 + r;
                const size_t id = (size_t)row * D_DIM + col;
                const float v1 = acc1[i][j][r];
                const float v2 = acc2[i][j][r];
                if constexpr (MODE == 0) {          // r, g
                    ((bf16_t*)out0)[id] = (bf16_t)sigmoid_f(v1);
                    ((bf16_t*)out1)[id] = (bf16_t)sigmoid_f(v2);
                } else {                            // k_ffn, fr
                    float t = fmaxf(v1 + bias0[col], 0.f);
                    ((bf16_t*)out0)[id] = (bf16_t)(t * t);
                    ((bf16_t*)out1)[id] = (bf16_t)sigmoid_f(v2 + bias1[col]);
                }
            }
        }
    }
}

// ---------------------------------------------------------------------------
// Fused u-kernel (r7-VERIFIED, reverted verbatim): u = (xm@Wk)*(xm@Wv) +
// (xm@Wa)*(xm@Wb). Two pair passes ({Wk,Wv}, {Wa,Wb}); A staged once per
// K-step. 256 thr, __launch_bounds__(256,2) [VGPR cap 256 — measured 128,
// no spill, 176.7 µs / 34.4% MfmaUtil]. Wt4 = Wk,Wv,Wa,Wb contiguous slots.
// ---------------------------------------------------------------------------
__global__ void __launch_bounds__(256, 2)
gemm_uv_kernel(const bf16_t* __restrict__ A, const bf16_t* __restrict__ Wt4,
               float* __restrict__ u)
{
    constexpr int K = D_DIM;
    constexpr size_t WSZ_E = (size_t)D_DIM * D_DIM;
    __shared__ bf16_t sA[2][128 * 32];      // 16 KB
    __shared__ bf16_t sB1[2][128 * 32];     // 16 KB
    __shared__ bf16_t sB2[2][128 * 32];     // 16 KB
    const int tid  = threadIdx.x;
    const int wave = tid >> 6, lane = tid & 63;

    const int lin = blockIdx.x;
    const int xcd = lin & 7;
    const int idx = lin >> 3;               // 0..127
    const int mt  = xcd * 16 + (idx >> 3);
    const int nt  = idx & 7;
    const int m0 = mt * 128, n0 = nt * 128;

    const int wm = (wave & 1) * 64, wn = (wave >> 1) * 64;

    const int rl = lane >> 2;
    const int cc = lane & 3;
    const int scol = (cc ^ ((rl >> 1) & 3)) * 8;
    const int srow = wave * 32 + rl;
    const bf16_t* gA  = A   + (size_t)(m0 + srow) * K + scol;
    const bf16_t* gB0 = Wt4 + (size_t)(n0 + srow) * K + scol;
    const int lofs = (wave * 32) * 32;

    const int fr = lane & 15;
    const int quad = lane >> 4;
    const int qs = (quad ^ ((fr >> 1) & 3)) * 8;

    // one pass: acc1 += A@B1, acc2 += A@B2, A staged once per K-step
    auto kloop2 = [&](const bf16_t* gB1, const bf16_t* gB2,
                      f32x4 (&acc1)[4][4], f32x4 (&acc2)[4][4]) {
        load_lds_16(gA,                    &sA[0][lofs]);
        load_lds_16(gA  + (size_t)16 * K,  &sA[0][lofs + 16 * 32]);
        load_lds_16(gB1,                   &sB1[0][lofs]);
        load_lds_16(gB1 + (size_t)16 * K,  &sB1[0][lofs + 16 * 32]);
        load_lds_16(gB2,                   &sB2[0][lofs]);
        load_lds_16(gB2 + (size_t)16 * K,  &sB2[0][lofs + 16 * 32]);
        __syncthreads();
        int cur = 0;
        for (int kk = 0; kk < K; kk += 32) {
            if (kk + 32 < K) {
                const int nb = cur ^ 1;
                load_lds_16(gA  + kk + 32,                   &sA[nb][lofs]);
                load_lds_16(gA  + (size_t)16 * K + kk + 32,  &sA[nb][lofs + 16 * 32]);
                load_lds_16(gB1 + kk + 32,                   &sB1[nb][lofs]);
                load_lds_16(gB1 + (size_t)16 * K + kk + 32,  &sB1[nb][lofs + 16 * 32]);
                load_lds_16(gB2 + kk + 32,                   &sB2[nb][lofs]);
                load_lds_16(gB2 + (size_t)16 * K + kk + 32,  &sB2[nb][lofs + 16 * 32]);
            }
            bf16x8 af[4], b1[4], b2[4];
            #pragma unroll
            for (int i = 0; i < 4; i++)
                af[i] = *(const bf16x8*)(&sA[cur][(wm + i * 16 + fr) * 32 + qs]);
            #pragma unroll
            for (int j = 0; j < 4; j++) {
                b1[j] = *(const bf16x8*)(&sB1[cur][(wn + j * 16 + fr) * 32 + qs]);
                b2[j] = *(const bf16x8*)(&sB2[cur][(wn + j * 16 + fr) * 32 + qs]);
            }
            #pragma unroll
            for (int i = 0; i < 4; i++)
                #pragma unroll
                for (int j = 0; j < 4; j++) {
                    acc1[i][j] = __builtin_amdgcn_mfma_f32_16x16x32_bf16(af[i], b1[j], acc1[i][j], 0, 0, 0);
                    acc2[i][j] = __builtin_amdgcn_mfma_f32_16x16x32_bf16(af[i], b2[j], acc2[i][j], 0, 0, 0);
                }
            __syncthreads();
            cur ^= 1;
        }
    };

    f32x4 aKV[4][4] = {};   // k, then k*v
    f32x4 aT[4][4]  = {};   // v, then a
    f32x4 aB2[4][4] = {};   // b

    kloop2(gB0, gB0 + WSZ_E, aKV, aT);          // k, v
    #pragma unroll
    for (int i = 0; i < 4; i++)
        #pragma unroll
        for (int j = 0; j < 4; j++) {
            aKV[i][j] = aKV[i][j] * aT[i][j];
            aT[i][j] = f32x4{0.f, 0.f, 0.f, 0.f};
        }
    kloop2(gB0 + 2 * WSZ_E, gB0 + 3 * WSZ_E, aT, aB2);   // a, b

    #pragma unroll
    for (int i = 0; i < 4; i++) {
        #pragma unroll
        for (int j = 0; j < 4; j++) {
            const int col = n0 + wn + j * 16 + fr;
            #pragma unroll
            for (int r = 0; r < 4; r++) {
                const int row = m0 + wm + i * 16 + quad * 4 + r;
                u[(size_t)row * D_DIM + col] =
                    aKV[i][j][r] + aT[i][j][r] * aB2[i][j][r];
            }
        }
    }
}

// ---------------------------------------------------------------------------
// Weight transpose + fp32->bf16:  Wt[n][k] = W[k][n]
// ---------------------------------------------------------------------------
struct WList { const float* w[NW]; };

__global__ void __launch_bounds__(256)
transpose_cvt_kernel(WList wl, bf16_t* wt_base)
{
    __shared__ float tile[32][33];
    const float* W = wl.w[blockIdx.z];
    bf16_t* Wt = wt_base + (size_t)blockIdx.z * D_DIM * D_DIM;
    const int bx = blockIdx.x * 32, by = blockIdx.y * 32;
    const int tx = threadIdx.x, ty = threadIdx.y;
    #pragma unroll
    for (int i = 0; i < 32; i += 8)
        tile[ty + i][tx] = W[(size_t)(by + ty + i) * D_DIM + bx + tx];
    __syncthreads();
    #pragma unroll
    for (int i = 0; i < 32; i += 8)
        Wt[(size_t)(bx + ty + i) * D_DIM + by + tx] = (bf16_t)tile[tx][ty + i];
}

// ---------------------------------------------------------------------------
// ew[d] = exp(decay[d])
// ---------------------------------------------------------------------------
__global__ void __launch_bounds__(256)
ew_kernel(const float* __restrict__ decay, float* __restrict__ ew)
{
    const int d = blockIdx.x * 256 + threadIdx.x;
    if (d < D_DIM) ew[d] = expf(decay[d]);
}

// ---------------------------------------------------------------------------
// LN1 of rows t and t-1, xm = 0.5*(xx_t + xx_{t-1}) -> bf16. One block per row.
// ---------------------------------------------------------------------------
__global__ void __launch_bounds__(256)
ln_shift_kernel(const float* __restrict__ x, const float* __restrict__ w,
                const float* __restrict__ bias, bf16_t* __restrict__ xm)
{
    const int row = blockIdx.x;
    const int t = row & (T_DIM - 1);
    const int d0 = threadIdx.x * 4;
    const float* xc = x + (size_t)row * D_DIM;
    f32x4 c = *(const f32x4*)(xc + d0);
    f32x4 p = {0.f, 0.f, 0.f, 0.f};
    if (t > 0) p = *(const f32x4*)(xc - D_DIM + d0);

    float sc = 0.f, qc = 0.f, sp = 0.f, qp = 0.f;
    #pragma unroll
    for (int e = 0; e < 4; e++) {
        sc += c[e]; qc += c[e] * c[e];
        sp += p[e]; qp += p[e] * p[e];
    }
    #pragma unroll
    for (int off = 32; off > 0; off >>= 1) {
        sc += __shfl_down(sc, off); qc += __shfl_down(qc, off);
        sp += __shfl_down(sp, off); qp += __shfl_down(qp, off);
    }
    __shared__ float red[16];
    const int wv = threadIdx.x >> 6, ln = threadIdx.x & 63;
    if (ln == 0) { red[wv] = sc; red[4 + wv] = qc; red[8 + wv] = sp; red[12 + wv] = qp; }
    __syncthreads();
    sc = red[0] + red[1] + red[2] + red[3];
    qc = red[4] + red[5] + red[6] + red[7];
    sp = red[8] + red[9] + red[10] + red[11];
    qp = red[12] + red[13] + red[14] + red[15];

    const float inv = 1.f / (float)D_DIM;
    const float mc = sc * inv, vc = qc * inv - mc * mc, rc = rsqrtf(vc + 1e-5f);
    const float mp = sp * inv, vp = qp * inv - mp * mp, rp = rsqrtf(vp + 1e-5f);

    bf16x4 o;
    #pragma unroll
    for (int e = 0; e < 4; e++) {
        const int d = d0 + e;
        const float wd = w[d], bd = bias[d];
        const float nc = (c[e] - mc) * rc * wd + bd;
        const float np = (t > 0) ? ((p[e] - mp) * rp * wd + bd) : 0.f;
        o[e] = (bf16_t)(0.5f * (nc + np));
    }
    *(bf16x4*)(xm + (size_t)row * D_DIM + d0) = o;
}

// ---------------------------------------------------------------------------
// scan pass 1: local chunk scans (zero init), IN-PLACE u -> states, + carry out
// ---------------------------------------------------------------------------
__global__ void __launch_bounds__(256)
scan1_kernel(float* __restrict__ u, const float* __restrict__ ew,
             float* __restrict__ carry)
{
    const int gid = blockIdx.x * 256 + threadIdx.x;   // (c*B + b)*D + d
    const int d = gid & (D_DIM - 1);
    const int b = (gid >> 10) & (B_DIM - 1);
    const int c = gid >> 13;
    const float w = expf(-ew[d]);
    float s = 0.f;
    const size_t base = ((size_t)b * T_DIM + (size_t)c * LCH) * D_DIM + d;
    #pragma unroll 4
    for (int tl = 0; tl < LCH; tl++) {
        const size_t idx = base + (size_t)tl * D_DIM;
        s = fmaf(s, w, u[idx]);
        u[idx] = s;
    }
    carry[(size_t)(b * CCH + c) * D_DIM + d] = s;
}

// ---------------------------------------------------------------------------
// scan pass 2: combine carries sequentially -> incoming per chunk + final state
// ---------------------------------------------------------------------------
__global__ void __launch_bounds__(256)
scan2_kernel(const float* __restrict__ s0, const float* __restrict__ ew,
             const float* __restrict__ carry, float* __restrict__ inc,
             float* __restrict__ fstate)
{
    const int gid = blockIdx.x * 256 + threadIdx.x;   // b*D + d
    const int d = gid & (D_DIM - 1);
    const int b = gid >> 10;
    const float wL = expf(-(float)LCH * ew[d]);
    float s = s0[gid];
    #pragma unroll
    for (int c = 0; c < CCH; c++) {
        const size_t idx = (size_t)(b * CCH + c) * D_DIM + d;
        inc[idx] = s;
        s = fmaf(s, wL, carry[idx]);
    }
    fstate[gid] = s;
}

// ---------------------------------------------------------------------------
// scan recombine + GroupNorm(32ch) + mixed = sr*ns*g -> bf16
// ---------------------------------------------------------------------------
__global__ void __launch_bounds__(256)
mixed_kernel(const float* __restrict__ st, const float* __restrict__ inc,
             const float* __restrict__ ew, const bf16_t* __restrict__ sr,
             const bf16_t* __restrict__ g, const float* __restrict__ gnw,
             const float* __restrict__ gnb, bf16_t* __restrict__ outp)
{
    const int row = blockIdx.x;                 // b*T + t
    const int b = row >> 11;
    const int t = row & (T_DIM - 1);
    const int c = t >> 7, tl = t & (LCH - 1);
    const int d0 = threadIdx.x * 4;
    const size_t base = (size_t)row * D_DIM + d0;

    f32x4 lv = *(const f32x4*)(st + base);
    f32x4 iv = *(const f32x4*)(inc + (size_t)(b * CCH + c) * D_DIM + d0);
    f32x4 ev = *(const f32x4*)(ew + d0);

    float s[4];
    float sum = 0.f, sq = 0.f;
    #pragma unroll
    for (int e = 0; e < 4; e++) {
        s[e] = lv[e] + expf(-(float)(tl + 1) * ev[e]) * iv[e];
        sum += s[e]; sq += s[e] * s[e];
    }
    // group of 32 channels == 8 consecutive lanes
    #pragma unroll
    for (int m = 1; m <= 4; m <<= 1) { sum += __shfl_xor(sum, m); sq += __shfl_xor(sq, m); }
    const float mean = sum * (1.f / 32.f);
    const float var  = sq * (1.f / 32.f) - mean * mean;
    const float rstd = rsqrtf(var + 1e-5f);

    bf16x4 rv = *(const bf16x4*)(sr + base);
    bf16x4 gv = *(const bf16x4*)(g + base);
    f32x4 wv = *(const f32x4*)(gnw + d0);
    f32x4 bv = *(const f32x4*)(gnb + d0);
    bf16x4 o;
    #pragma unroll
    for (int e = 0; e < 4; e++) {
        const float ns = (s[e] - mean) * rstd * wv[e] + bv[e];
        o[e] = (bf16_t)((float)rv[e] * ns * (float)gv[e]);
    }
    *(bf16x4*)(outp + base) = o;
}

// ---------------------------------------------------------------------------
// LN2: read x2, write normalized bf16
// ---------------------------------------------------------------------------
__global__ void __launch_bounds__(256)
ln2_kernel(const float* __restrict__ x2, const float* __restrict__ w,
           const float* __restrict__ bias, bf16_t* __restrict__ xx2)
{
    const int row = blockIdx.x;
    const int d0 = threadIdx.x * 4;
    const float* xc = x2 + (size_t)row * D_DIM;
    f32x4 c = *(const f32x4*)(xc + d0);
    float sc = 0.f, qc = 0.f;
    #pragma unroll
    for (int e = 0; e < 4; e++) { sc += c[e]; qc += c[e] * c[e]; }
    #pragma unroll
    for (int off = 32; off > 0; off >>= 1) {
        sc += __shfl_down(sc, off); qc += __shfl_down(qc, off);
    }
    __shared__ float red[8];
    const int wv = threadIdx.x >> 6, ln = threadIdx.x & 63;
    if (ln == 0) { red[wv] = sc; red[4 + wv] = qc; }
    __syncthreads();
    sc = red[0] + red[1] + red[2] + red[3];
    qc = red[4] + red[5] + red[6] + red[7];
    const float inv = 1.f / (float)D_DIM;
    const float m = sc * inv, v = qc * inv - m * m, rs = rsqrtf(v + 1e-5f);
    bf16x4 o;
    #pragma unroll
    for (int e = 0; e < 4; e++) {
        const int d = d0 + e;
        o[e] = (bf16_t)((c[e] - m) * rs * w[d] + bias[d]);
    }
    *(bf16x4*)(xx2 + (size_t)row * D_DIM + d0) = o;
}

// ---------------------------------------------------------------------------
// GRN pass 2: gx = sqrt(sum over 8 m-tile partials), nx = gx/(mean_d(gx)+1e-6)
// ---------------------------------------------------------------------------
__global__ void __launch_bounds__(1024)
grn2_kernel(const float* __restrict__ partial, float* __restrict__ nx)
{
    const int b = blockIdx.x, d = threadIdx.x;
    float s = 0.f;
    #pragma unroll
    for (int c = 0; c < 8; c++) s += partial[(size_t)(b * 8 + c) * D_DIM + d];
    const float gx = sqrtf(s);
    float v = gx;
    #pragma unroll
    for (int off = 32; off > 0; off >>= 1) v += __shfl_down(v, off);
    __shared__ float red[16];
    if ((threadIdx.x & 63) == 0) red[threadIdx.x >> 6] = v;
    __syncthreads();
    float tot = 0.f;
    #pragma unroll
    for (int i = 0; i < 16; i++) tot += red[i];
    nx[b * D_DIM + d] = gx / (tot * (1.f / (float)D_DIM) + 1e-6f);
}

// ---------------------------------------------------------------------------
// frh = fr * (gamma*(h*nx) + beta + h) -> bf16
// ---------------------------------------------------------------------------
__global__ void __launch_bounds__(256)
frh_kernel(const float* __restrict__ h, const bf16_t* __restrict__ fr,
           const float* __restrict__ nx, const float* __restrict__ gamma,
           const float* __restrict__ beta, bf16_t* __restrict__ outp)
{
    const size_t gid = (size_t)blockIdx.x * 256 + threadIdx.x;
    const size_t i4 = gid * 4;
    const int d = (int)(i4 & (D_DIM - 1));
    const int b = (int)(i4 >> 21);     // T*D = 2^21
    f32x4 hv = *(const f32x4*)(h + i4);
    bf16x4 fv = *(const bf16x4*)(fr + i4);
    f32x4 nv = *(const f32x4*)(nx + (size_t)b * D_DIM + d);
    f32x4 gm = *(const f32x4*)(gamma + d);
    f32x4 bt = *(const f32x4*)(beta + d);
    bf16x4 o;
    #pragma unroll
    for (int e = 0; e < 4; e++) {
        const float hh = hv[e];
        const float val = gm[e] * (hh * nv[e]) + bt[e] + hh;
        o[e] = (bf16_t)((float)fv[e] * val);
    }
    *(bf16x4*)(outp + i4) = o;
}

// ---------------------------------------------------------------------------
extern "C" void kernel_launch(void* const* d_in, const int* in_sizes, int n_in,
                              void* d_out, int out_size, void* d_ws, size_t ws_size,
                              hipStream_t stream)
{
    (void)in_sizes; (void)n_in; (void)out_size; (void)ws_size;

    const float* x      = (const float*)d_in[0];
    const float* state0 = (const float*)d_in[1];
    const float* ln1_w  = (const float*)d_in[2];
    const float* ln1_b  = (const float*)d_in[3];
    const float* ln2_w  = (const float*)d_in[4];
    const float* ln2_b  = (const float*)d_in[5];
    const float* gn_w   = (const float*)d_in[6];
    const float* gn_b   = (const float*)d_in[7];
    const float* grn_g  = (const float*)d_in[8];
    const float* grn_b  = (const float*)d_in[9];
    const float* decay  = (const float*)d_in[10];
    const float* bfk    = (const float*)d_in[20];
    const float* bfv    = (const float*)d_in[22];
    const float* bfr    = (const float*)d_in[24];

    // workspace layout (~223 MB total)
    const size_t WSZ = (size_t)D_DIM * D_DIM;
    float*  F1 = (float*)d_ws;         // u -> states -> h        (fp32, 64MB)
    bf16_t* B0 = (bf16_t*)(F1 + SZ);   // xm -> xx2               (bf16, 32MB)
    bf16_t* B1 = B0 + SZ;              // mixed -> k_ffn
    bf16_t* B2 = B1 + SZ;              // sr=sigmoid(r) -> fr
    bf16_t* B3 = B2 + SZ;              // g -> frh
    bf16_t* WT = B3 + SZ;              // 11 transposed bf16 weights (22MB)
    float*  carry   = (float*)(WT + NW * WSZ);
    float*  inc     = carry + (size_t)B_DIM * CCH * D_DIM;
    float*  partial = inc + (size_t)B_DIM * CCH * D_DIM;   // 64 x D grn partials
    float*  nxp     = partial + (size_t)64 * D_DIM;
    float*  ewp     = nxp + (size_t)B_DIM * D_DIM;

    // weight slots (fusion-contiguous):
    // 0 Wr, 1 Wg (pair proj), 2 Wk, 3 Wv, 4 Wa, 5 Wb (uv),
    // 6 Wout, 7 Wfk, 8 Wfr (pair ffn), 9 Wfv, 10 Wffnout
    WList wl;
    const int widx[NW] = {11, 14, 12, 13, 15, 16, 17, 19, 23, 21, 18};
    for (int i = 0; i < NW; i++) wl.w[i] = (const float*)d_in[widx[i]];

    float* out_x  = (float*)d_out;
    float* out_st = out_x + SZ;

    transpose_cvt_kernel<<<dim3(32, 32, NW), dim3(32, 8), 0, stream>>>(wl, WT);
    ew_kernel<<<4, 256, 0, stream>>>(decay, ewp);
    ln_shift_kernel<<<M_DIM, 256, 0, stream>>>(x, ln1_w, ln1_b, B0);

    // pair proj: sr=sigmoid(xm@Wr)->B2, g=sigmoid(xm@Wg)->B3
    gemm_pair_kernel<0><<<1024, 256, 0, stream>>>(
        B0, WT + 0 * WSZ, WT + 1 * WSZ, B2, B3, nullptr, nullptr);
    // u = (xm@Wk)*(xm@Wv) + (xm@Wa)*(xm@Wb)  -> F1 (single write)
    gemm_uv_kernel<<<1024, 256, 0, stream>>>(B0, WT + 2 * WSZ, F1);

    scan1_kernel<<<(CCH * B_DIM * D_DIM) / 256, 256, 0, stream>>>(F1, ewp, carry);
    scan2_kernel<<<(B_DIM * D_DIM) / 256, 256, 0, stream>>>(state0, ewp, carry, inc, out_st);
    mixed_kernel<<<M_DIM, 256, 0, stream>>>(F1, inc, ewp, B2, B3, gn_w, gn_b, B1);

    // x2 = x + mixed @ Wout  -> directly into d_out
    gemm2_kernel<8, 3><<<512, 512, 0, stream>>>(
        B1, WT + 6 * WSZ, out_x, nullptr, nullptr, nullptr, x);
    ln2_kernel<<<M_DIM, 256, 0, stream>>>(out_x, ln2_w, ln2_b, B0);

    // pair ffn: k_ffn = relu^2(xx2@Wfk + bfk)->B1, fr = sigmoid(xx2@Wfr + bfr)->B2
    gemm_pair_kernel<1><<<1024, 256, 0, stream>>>(
        B0, WT + 7 * WSZ, WT + 8 * WSZ, B1, B2, bfk, bfr);
    // h = k_ffn @ Wfv + bfv -> F1, plus grn h^2 partials -> partial (MODE 7)
    gemm2_kernel<8, 7><<<512, 512, 0, stream>>>(
        B1, WT + 9 * WSZ, F1, partial, bfv, nullptr, nullptr);

    grn2_kernel<<<B_DIM, 1024, 0, stream>>>(partial, nxp);
    frh_kernel<<<M_DIM, 256, 0, stream>>>(F1, B2, nxp, grn_g, grn_b, B3);

    // out = x2 + frh @ Wffnout  (in-place accumulate into d_out)
    gemm2_kernel<8, 3><<<512, 512, 0, stream>>>(
        B3, WT + 10 * WSZ, out_x, nullptr, nullptr, nullptr, out_x);
}

// Round 10
// 835.331 us; speedup vs baseline: 3.4254x; 1.0180x over previous
//
#include <hip/hip_runtime.h>
#include <hip/hip_bf16.h>
#include <math.h>

#define D_DIM 1024
#define T_DIM 2048
#define B_DIM 8
#define M_DIM (B_DIM * T_DIM)          // 16384
#define SZ ((size_t)M_DIM * D_DIM)     // 16777216
#define NW 11
#define CCH 16                          // scan chunks
#define LCH 128                         // scan chunk length

typedef __bf16 bf16_t;
typedef __bf16 bf16x8 __attribute__((ext_vector_type(8)));
typedef __bf16 bf16x4 __attribute__((ext_vector_type(4)));
typedef float f32x4 __attribute__((ext_vector_type(4)));

typedef const __attribute__((address_space(1))) void* as1_const_ptr;
typedef __attribute__((address_space(3))) void* as3_ptr;

__device__ __forceinline__ void load_lds_16(const void* g, void* l) {
    __builtin_amdgcn_global_load_lds((as1_const_ptr)g, (as3_ptr)l, 16, 0, 0);
}

__device__ __forceinline__ float sigmoid_f(float x) { return 1.f / (1.f + expf(-x)); }

// ---------------------------------------------------------------------------
// GEMM v5 (r6-verified): 256x128 tile, BK=32, 512 thr (8 waves 4x2; per-wave
// 64x64 out via 4x4 mfma 16x16x32). 2-phase double-buffered K-loop, chunk
// XOR-swizzle (chunk ^= (row>>1)&3) on global source + fragment read.
// __launch_bounds__(512,4) [VGPR cap 128 — OK: 1 acc set ~100 live].
// XCD swizzle: xcd = lin&7.
//
// MODE epilogues:
//  3: out0 fp32 = acc + other_f32  (residual; may alias)  (Wout, Wffnout)
//  7: h = acc + bias0 -> out0 fp32, PLUS grn partial: out1[mt*D + col] =
//     sum over the block's 256 rows of h^2 (quad-shfl + LDS wave reduce).
// ---------------------------------------------------------------------------
template<int NT, int MODE>
__global__ void __launch_bounds__(512, 4)
gemm2_kernel(const bf16_t* __restrict__ A, const bf16_t* __restrict__ Bt,
             void* __restrict__ out0, void* __restrict__ out1,
             const float* __restrict__ bias0, const float* __restrict__ bias1,
             const void* __restrict__ other)
{
    constexpr int K = D_DIM;
    __shared__ bf16_t sA[2][256 * 32];      // 32 KB
    __shared__ bf16_t sB[2][128 * 32];      // 16 KB
    __shared__ float gsum[8][64];           // 2 KB (MODE 7 reduce)
    const int tid  = threadIdx.x;
    const int wave = tid >> 6, lane = tid & 63;

    const int lin = blockIdx.x;
    const int xcd = lin & 7;
    const int idx = lin >> 3;               // 0 .. 8*NT-1
    const int mt  = xcd * 8 + idx / NT;     // 0..63
    const int nt  = idx % NT;
    const int m0 = mt * 256, n0 = nt * 128;

    const int wm = (wave & 3) * 64;         // 0..192
    const int wn = (wave >> 2) * 64;        // 0 / 64

    const int rl = lane >> 2;
    const int cc = lane & 3;
    const int scol = (cc ^ ((rl >> 1) & 3)) * 8;
    const bf16_t* gA = A  + (size_t)(m0 + wave * 32 + rl) * K + scol;
    const bf16_t* gB = Bt + (size_t)(n0 + wave * 16 + rl) * K + scol;
    const int lofsA = (wave * 32) * 32;
    const int lofsB = (wave * 16) * 32;

    f32x4 acc[4][4] = {};

    const int fr = lane & 15;
    const int quad = lane >> 4;
    const int qs = (quad ^ ((fr >> 1) & 3)) * 8;   // swizzled fragment chunk

    load_lds_16(gA,                   &sA[0][lofsA]);
    load_lds_16(gA + (size_t)16 * K,  &sA[0][lofsA + 16 * 32]);
    load_lds_16(gB,                   &sB[0][lofsB]);
    __syncthreads();

    int cur = 0;
    for (int kk = 0; kk < K; kk += 32) {
        if (kk + 32 < K) {
            const int nb = cur ^ 1;
            load_lds_16(gA + kk + 32,                   &sA[nb][lofsA]);
            load_lds_16(gA + (size_t)16 * K + kk + 32,  &sA[nb][lofsA + 16 * 32]);
            load_lds_16(gB + kk + 32,                   &sB[nb][lofsB]);
        }
        bf16x8 af[4], bq[4];
        #pragma unroll
        for (int i = 0; i < 4; i++)
            af[i] = *(const bf16x8*)(&sA[cur][(wm + i * 16 + fr) * 32 + qs]);
        #pragma unroll
        for (int j = 0; j < 4; j++)
            bq[j] = *(const bf16x8*)(&sB[cur][(wn + j * 16 + fr) * 32 + qs]);
        #pragma unroll
        for (int i = 0; i < 4; i++)
            #pragma unroll
            for (int j = 0; j < 4; j++)
                acc[i][j] = __builtin_amdgcn_mfma_f32_16x16x32_bf16(af[i], bq[j], acc[i][j], 0, 0, 0);
        __syncthreads();
        cur ^= 1;
    }

    float hs[4] = {0.f, 0.f, 0.f, 0.f};     // MODE 7 per-col h^2 partials

    #pragma unroll
    for (int i = 0; i < 4; i++) {
        #pragma unroll
        for (int j = 0; j < 4; j++) {
            const int col = n0 + wn + j * 16 + fr;
            #pragma unroll
            for (int r = 0; r < 4; r++) {
                const int row = m0 + wm + i * 16 + quad * 4 + r;
                float v = acc[i][j][r];
                if constexpr (MODE == 3) {
                    const size_t id = (size_t)row * D_DIM + col;
                    ((float*)out0)[id] = v + ((const float*)other)[id];
                } else {                                    // MODE 7: h + grn
                    const float h = v + bias0[col];
                    ((float*)out0)[(size_t)row * D_DIM + col] = h;
                    hs[j] += h * h;
                }
            }
        }
    }

    if constexpr (MODE == 7) {
        #pragma unroll
        for (int j = 0; j < 4; j++) {
            float t = hs[j];
            t += __shfl_xor(t, 16);
            t += __shfl_xor(t, 32);
            if (lane < 16) gsum[wave][j * 16 + fr] = t;
        }
        __syncthreads();
        if (tid < 128) {
            const int p = tid >> 6, jf = tid & 63;   // p = wn half
            const float tot = gsum[4 * p + 0][jf] + gsum[4 * p + 1][jf]
                            + gsum[4 * p + 2][jf] + gsum[4 * p + 3][jf];
            ((float*)out1)[(size_t)mt * D_DIM + n0 + p * 64 + jf] = tot;
        }
    }
}

// ---------------------------------------------------------------------------
// PAIR GEMM v2: 256x128 tile, A staged once + TWO B panels per K-step
// (32KB per 4 MFMA-units = 8 KB/unit vs the 128^2-pair's 12 — the measured
// panels->time proportionality predicts ~0.67x). 512 thr (8 waves 4x2),
// __launch_bounds__(512,2) [VGPR cap 256 — 2 acc sets + frags ~195 fit;
// (512,4)'s 128 cap spilled in r8], 64 KB LDS, 1 block/CU (8 waves, same
// total waves/CU as the r9 2x4-wave version). Staging/fragment geometry
// identical to r6-verified gemm2; second B panel staged identically.
//
// MODE 0 (r,g):   out0 = sigmoid(acc1) bf16, out1 = sigmoid(acc2) bf16
// MODE 1 (ffn):   out0 = relu^2(acc1+bias0) bf16, out1 = sigmoid(acc2+bias1)
// ---------------------------------------------------------------------------
template<int MODE>
__global__ void __launch_bounds__(512, 2)
gemm_pair_kernel(const bf16_t* __restrict__ A, const bf16_t* __restrict__ B1t,
                 const bf16_t* __restrict__ B2t,
                 void* __restrict__ out0, void* __restrict__ out1,
                 const float* __restrict__ bias0, const float* __restrict__ bias1)
{
    constexpr int K = D_DIM;
    __shared__ bf16_t sA[2][256 * 32];      // 32 KB
    __shared__ bf16_t sB1[2][128 * 32];     // 16 KB
    __shared__ bf16_t sB2[2][128 * 32];     // 16 KB
    const int tid  = threadIdx.x;
    const int wave = tid >> 6, lane = tid & 63;

    const int lin = blockIdx.x;             // grid = 512 (8 xcd x 8 mt x 8 nt)
    const int xcd = lin & 7;
    const int idx = lin >> 3;               // 0..63
    const int mt  = xcd * 8 + (idx >> 3);   // 0..63
    const int nt  = idx & 7;
    const int m0 = mt * 256, n0 = nt * 128;

    const int wm = (wave & 3) * 64;         // 0..192
    const int wn = (wave >> 2) * 64;        // 0 / 64

    const int rl = lane >> 2;
    const int cc = lane & 3;
    const int scol = (cc ^ ((rl >> 1) & 3)) * 8;
    const bf16_t* gA  = A   + (size_t)(m0 + wave * 32 + rl) * K + scol;
    const bf16_t* gB1 = B1t + (size_t)(n0 + wave * 16 + rl) * K + scol;
    const bf16_t* gB2 = B2t + (size_t)(n0 + wave * 16 + rl) * K + scol;
    const int lofsA = (wave * 32) * 32;
    const int lofsB = (wave * 16) * 32;

    f32x4 acc1[4][4] = {}, acc2[4][4] = {};

    const int fr = lane & 15;
    const int quad = lane >> 4;
    const int qs = (quad ^ ((fr >> 1) & 3)) * 8;

    load_lds_16(gA,                   &sA[0][lofsA]);
    load_lds_16(gA + (size_t)16 * K,  &sA[0][lofsA + 16 * 32]);
    load_lds_16(gB1,                  &sB1[0][lofsB]);
    load_lds_16(gB2,                  &sB2[0][lofsB]);
    __syncthreads();

    int cur = 0;
    for (int kk = 0; kk < K; kk += 32) {
        if (kk + 32 < K) {
            const int nb = cur ^ 1;
            load_lds_16(gA + kk + 32,                   &sA[nb][lofsA]);
            load_lds_16(gA + (size_t)16 * K + kk + 32,  &sA[nb][lofsA + 16 * 32]);
            load_lds_16(gB1 + kk + 32,                  &sB1[nb][lofsB]);
            load_lds_16(gB2 + kk + 32,                  &sB2[nb][lofsB]);
        }
        bf16x8 af[4], b1[4], b2[4];
        #pragma unroll
        for (int i = 0; i < 4; i++)
            af[i] = *(const bf16x8*)(&sA[cur][(wm + i * 16 + fr) * 32 + qs]);
        #pragma unroll
        for (int j = 0; j < 4; j++) {
            b1[j] = *(const bf16x8*)(&sB1[cur][(wn + j * 16 + fr) * 32 + qs]);
            b2[j] = *(const bf16x8*)(&sB2[cur][(wn + j * 16 + fr) * 32 + qs]);
        }
        #pragma unroll
        for (int i = 0; i < 4; i++)
            #pragma unroll
            for (int j = 0; j < 4; j++) {
                acc1[i][j] = __builtin_amdgcn_mfma_f32_16x16x32_bf16(af[i], b1[j], acc1[i][j], 0, 0, 0);
                acc2[i][j] = __builtin_amdgcn_mfma_f32_16x16x32_bf16(af[i], b2[j], acc2[i][j], 0, 0, 0);
            }
        __syncthreads();
        cur ^= 1;
    }

    #pragma unroll
    for (int i = 0; i < 4; i++) {
        #pragma unroll
        for (int j = 0; j < 4; j++) {
            const int col = n0 + wn + j * 16 + fr;
            #pragma unroll
            for (int r = 0; r < 4; r++) {
                const int row = m0 + wm + i * 16 + quad * 4 + r;
                const size_t id = (size_t)row * D_DIM + col;
                const float v1 = acc1[i][j][r];
                const float v2 = acc2[i][j][r];
                if constexpr (MODE == 0) {          // r, g
                    ((bf16_t*)out0)[id] = (bf16_t)sigmoid_f(v1);
                    ((bf16_t*)out1)[id] = (bf16_t)sigmoid_f(v2);
                } else {                            // k_ffn, fr
                    float t = fmaxf(v1 + bias0[col], 0.f);
                    ((bf16_t*)out0)[id] = (bf16_t)(t * t);
                    ((bf16_t*)out1)[id] = (bf16_t)sigmoid_f(v2 + bias1[col]);
                }
            }
        }
    }
}

// ---------------------------------------------------------------------------
// Fused u-kernel (r9-VERIFIED, unchanged): u = (xm@Wk)*(xm@Wv) +
// (xm@Wa)*(xm@Wb). Two pair passes ({Wk,Wv}, {Wa,Wb}); A staged once per
// K-step. 256 thr, __launch_bounds__(256,2). NOT converted to 256x128:
// pass-2 liveness is 3 acc sets (~250 combined regs) — right at the 256 cap,
// r8-style silent-spill risk. Wt4 = Wk,Wv,Wa,Wb contiguous slots.
// ---------------------------------------------------------------------------
__global__ void __launch_bounds__(256, 2)
gemm_uv_kernel(const bf16_t* __restrict__ A, const bf16_t* __restrict__ Wt4,
               float* __restrict__ u)
{
    constexpr int K = D_DIM;
    constexpr size_t WSZ_E = (size_t)D_DIM * D_DIM;
    __shared__ bf16_t sA[2][128 * 32];      // 16 KB
    __shared__ bf16_t sB1[2][128 * 32];     // 16 KB
    __shared__ bf16_t sB2[2][128 * 32];     // 16 KB
    const int tid  = threadIdx.x;
    const int wave = tid >> 6, lane = tid & 63;

    const int lin = blockIdx.x;
    const int xcd = lin & 7;
    const int idx = lin >> 3;               // 0..127
    const int mt  = xcd * 16 + (idx >> 3);
    const int nt  = idx & 7;
    const int m0 = mt * 128, n0 = nt * 128;

    const int wm = (wave & 1) * 64, wn = (wave >> 1) * 64;

    const int rl = lane >> 2;
    const int cc = lane & 3;
    const int scol = (cc ^ ((rl >> 1) & 3)) * 8;
    const int srow = wave * 32 + rl;
    const bf16_t* gA  = A   + (size_t)(m0 + srow) * K + scol;
    const bf16_t* gB0 = Wt4 + (size_t)(n0 + srow) * K + scol;
    const int lofs = (wave * 32) * 32;

    const int fr = lane & 15;
    const int quad = lane >> 4;
    const int qs = (quad ^ ((fr >> 1) & 3)) * 8;

    // one pass: acc1 += A@B1, acc2 += A@B2, A staged once per K-step
    auto kloop2 = [&](const bf16_t* gB1, const bf16_t* gB2,
                      f32x4 (&acc1)[4][4], f32x4 (&acc2)[4][4]) {
        load_lds_16(gA,                    &sA[0][lofs]);
        load_lds_16(gA  + (size_t)16 * K,  &sA[0][lofs + 16 * 32]);
        load_lds_16(gB1,                   &sB1[0][lofs]);
        load_lds_16(gB1 + (size_t)16 * K,  &sB1[0][lofs + 16 * 32]);
        load_lds_16(gB2,                   &sB2[0][lofs]);
        load_lds_16(gB2 + (size_t)16 * K,  &sB2[0][lofs + 16 * 32]);
        __syncthreads();
        int cur = 0;
        for (int kk = 0; kk < K; kk += 32) {
            if (kk + 32 < K) {
                const int nb = cur ^ 1;
                load_lds_16(gA  + kk + 32,                   &sA[nb][lofs]);
                load_lds_16(gA  + (size_t)16 * K + kk + 32,  &sA[nb][lofs + 16 * 32]);
                load_lds_16(gB1 + kk + 32,                   &sB1[nb][lofs]);
                load_lds_16(gB1 + (size_t)16 * K + kk + 32,  &sB1[nb][lofs + 16 * 32]);
                load_lds_16(gB2 + kk + 32,                   &sB2[nb][lofs]);
                load_lds_16(gB2 + (size_t)16 * K + kk + 32,  &sB2[nb][lofs + 16 * 32]);
            }
            bf16x8 af[4], b1[4], b2[4];
            #pragma unroll
            for (int i = 0; i < 4; i++)
                af[i] = *(const bf16x8*)(&sA[cur][(wm + i * 16 + fr) * 32 + qs]);
            #pragma unroll
            for (int j = 0; j < 4; j++) {
                b1[j] = *(const bf16x8*)(&sB1[cur][(wn + j * 16 + fr) * 32 + qs]);
                b2[j] = *(const bf16x8*)(&sB2[cur][(wn + j * 16 + fr) * 32 + qs]);
            }
            #pragma unroll
            for (int i = 0; i < 4; i++)
                #pragma unroll
                for (int j = 0; j < 4; j++) {
                    acc1[i][j] = __builtin_amdgcn_mfma_f32_16x16x32_bf16(af[i], b1[j], acc1[i][j], 0, 0, 0);
                    acc2[i][j] = __builtin_amdgcn_mfma_f32_16x16x32_bf16(af[i], b2[j], acc2[i][j], 0, 0, 0);
                }
            __syncthreads();
            cur ^= 1;
        }
    };

    f32x4 aKV[4][4] = {};   // k, then k*v
    f32x4 aT[4][4]  = {};   // v, then a
    f32x4 aB2[4][4] = {};   // b

    kloop2(gB0, gB0 + WSZ_E, aKV, aT);          // k, v
    #pragma unroll
    for (int i = 0; i < 4; i++)
        #pragma unroll
        for (int j = 0; j < 4; j++) {
            aKV[i][j] = aKV[i][j] * aT[i][j];
            aT[i][j] = f32x4{0.f, 0.f, 0.f, 0.f};
        }
    kloop2(gB0 + 2 * WSZ_E, gB0 + 3 * WSZ_E, aT, aB2);   // a, b

    #pragma unroll
    for (int i = 0; i < 4; i++) {
        #pragma unroll
        for (int j = 0; j < 4; j++) {
            const int col = n0 + wn + j * 16 + fr;
            #pragma unroll
            for (int r = 0; r < 4; r++) {
                const int row = m0 + wm + i * 16 + quad * 4 + r;
                u[(size_t)row * D_DIM + col] =
                    aKV[i][j][r] + aT[i][j][r] * aB2[i][j][r];
            }
        }
    }
}

// ---------------------------------------------------------------------------
// Weight transpose + fp32->bf16:  Wt[n][k] = W[k][n]
// ---------------------------------------------------------------------------
struct WList { const float* w[NW]; };

__global__ void __launch_bounds__(256)
transpose_cvt_kernel(WList wl, bf16_t* wt_base)
{
    __shared__ float tile[32][33];
    const float* W = wl.w[blockIdx.z];
    bf16_t* Wt = wt_base + (size_t)blockIdx.z * D_DIM * D_DIM;
    const int bx = blockIdx.x * 32, by = blockIdx.y * 32;
    const int tx = threadIdx.x, ty = threadIdx.y;
    #pragma unroll
    for (int i = 0; i < 32; i += 8)
        tile[ty + i][tx] = W[(size_t)(by + ty + i) * D_DIM + bx + tx];
    __syncthreads();
    #pragma unroll
    for (int i = 0; i < 32; i += 8)
        Wt[(size_t)(bx + ty + i) * D_DIM + by + tx] = (bf16_t)tile[tx][ty + i];
}

// ---------------------------------------------------------------------------
// ew[d] = exp(decay[d])
// ---------------------------------------------------------------------------
__global__ void __launch_bounds__(256)
ew_kernel(const float* __restrict__ decay, float* __restrict__ ew)
{
    const int d = blockIdx.x * 256 + threadIdx.x;
    if (d < D_DIM) ew[d] = expf(decay[d]);
}

// ---------------------------------------------------------------------------
// LN1 of rows t and t-1, xm = 0.5*(xx_t + xx_{t-1}) -> bf16. One block per row.
// ---------------------------------------------------------------------------
__global__ void __launch_bounds__(256)
ln_shift_kernel(const float* __restrict__ x, const float* __restrict__ w,
                const float* __restrict__ bias, bf16_t* __restrict__ xm)
{
    const int row = blockIdx.x;
    const int t = row & (T_DIM - 1);
    const int d0 = threadIdx.x * 4;
    const float* xc = x + (size_t)row * D_DIM;
    f32x4 c = *(const f32x4*)(xc + d0);
    f32x4 p = {0.f, 0.f, 0.f, 0.f};
    if (t > 0) p = *(const f32x4*)(xc - D_DIM + d0);

    float sc = 0.f, qc = 0.f, sp = 0.f, qp = 0.f;
    #pragma unroll
    for (int e = 0; e < 4; e++) {
        sc += c[e]; qc += c[e] * c[e];
        sp += p[e]; qp += p[e] * p[e];
    }
    #pragma unroll
    for (int off = 32; off > 0; off >>= 1) {
        sc += __shfl_down(sc, off); qc += __shfl_down(qc, off);
        sp += __shfl_down(sp, off); qp += __shfl_down(qp, off);
    }
    __shared__ float red[16];
    const int wv = threadIdx.x >> 6, ln = threadIdx.x & 63;
    if (ln == 0) { red[wv] = sc; red[4 + wv] = qc; red[8 + wv] = sp; red[12 + wv] = qp; }
    __syncthreads();
    sc = red[0] + red[1] + red[2] + red[3];
    qc = red[4] + red[5] + red[6] + red[7];
    sp = red[8] + red[9] + red[10] + red[11];
    qp = red[12] + red[13] + red[14] + red[15];

    const float inv = 1.f / (float)D_DIM;
    const float mc = sc * inv, vc = qc * inv - mc * mc, rc = rsqrtf(vc + 1e-5f);
    const float mp = sp * inv, vp = qp * inv - mp * mp, rp = rsqrtf(vp + 1e-5f);

    bf16x4 o;
    #pragma unroll
    for (int e = 0; e < 4; e++) {
        const int d = d0 + e;
        const float wd = w[d], bd = bias[d];
        const float nc = (c[e] - mc) * rc * wd + bd;
        const float np = (t > 0) ? ((p[e] - mp) * rp * wd + bd) : 0.f;
        o[e] = (bf16_t)(0.5f * (nc + np));
    }
    *(bf16x4*)(xm + (size_t)row * D_DIM + d0) = o;
}

// ---------------------------------------------------------------------------
// scan pass 1: local chunk scans (zero init), IN-PLACE u -> states, + carry out
// ---------------------------------------------------------------------------
__global__ void __launch_bounds__(256)
scan1_kernel(float* __restrict__ u, const float* __restrict__ ew,
             float* __restrict__ carry)
{
    const int gid = blockIdx.x * 256 + threadIdx.x;   // (c*B + b)*D + d
    const int d = gid & (D_DIM - 1);
    const int b = (gid >> 10) & (B_DIM - 1);
    const int c = gid >> 13;
    const float w = expf(-ew[d]);
    float s = 0.f;
    const size_t base = ((size_t)b * T_DIM + (size_t)c * LCH) * D_DIM + d;
    #pragma unroll 4
    for (int tl = 0; tl < LCH; tl++) {
        const size_t idx = base + (size_t)tl * D_DIM;
        s = fmaf(s, w, u[idx]);
        u[idx] = s;
    }
    carry[(size_t)(b * CCH + c) * D_DIM + d] = s;
}

// ---------------------------------------------------------------------------
// scan pass 2: combine carries sequentially -> incoming per chunk + final state
// ---------------------------------------------------------------------------
__global__ void __launch_bounds__(256)
scan2_kernel(const float* __restrict__ s0, const float* __restrict__ ew,
             const float* __restrict__ carry, float* __restrict__ inc,
             float* __restrict__ fstate)
{
    const int gid = blockIdx.x * 256 + threadIdx.x;   // b*D + d
    const int d = gid & (D_DIM - 1);
    const int b = gid >> 10;
    const float wL = expf(-(float)LCH * ew[d]);
    float s = s0[gid];
    #pragma unroll
    for (int c = 0; c < CCH; c++) {
        const size_t idx = (size_t)(b * CCH + c) * D_DIM + d;
        inc[idx] = s;
        s = fmaf(s, wL, carry[idx]);
    }
    fstate[gid] = s;
}

// ---------------------------------------------------------------------------
// scan recombine + GroupNorm(32ch) + mixed = sr*ns*g -> bf16
// ---------------------------------------------------------------------------
__global__ void __launch_bounds__(256)
mixed_kernel(const float* __restrict__ st, const float* __restrict__ inc,
             const float* __restrict__ ew, const bf16_t* __restrict__ sr,
             const bf16_t* __restrict__ g, const float* __restrict__ gnw,
             const float* __restrict__ gnb, bf16_t* __restrict__ outp)
{
    const int row = blockIdx.x;                 // b*T + t
    const int b = row >> 11;
    const int t = row & (T_DIM - 1);
    const int c = t >> 7, tl = t & (LCH - 1);
    const int d0 = threadIdx.x * 4;
    const size_t base = (size_t)row * D_DIM + d0;

    f32x4 lv = *(const f32x4*)(st + base);
    f32x4 iv = *(const f32x4*)(inc + (size_t)(b * CCH + c) * D_DIM + d0);
    f32x4 ev = *(const f32x4*)(ew + d0);

    float s[4];
    float sum = 0.f, sq = 0.f;
    #pragma unroll
    for (int e = 0; e < 4; e++) {
        s[e] = lv[e] + expf(-(float)(tl + 1) * ev[e]) * iv[e];
        sum += s[e]; sq += s[e] * s[e];
    }
    // group of 32 channels == 8 consecutive lanes
    #pragma unroll
    for (int m = 1; m <= 4; m <<= 1) { sum += __shfl_xor(sum, m); sq += __shfl_xor(sq, m); }
    const float mean = sum * (1.f / 32.f);
    const float var  = sq * (1.f / 32.f) - mean * mean;
    const float rstd = rsqrtf(var + 1e-5f);

    bf16x4 rv = *(const bf16x4*)(sr + base);
    bf16x4 gv = *(const bf16x4*)(g + base);
    f32x4 wv = *(const f32x4*)(gnw + d0);
    f32x4 bv = *(const f32x4*)(gnb + d0);
    bf16x4 o;
    #pragma unroll
    for (int e = 0; e < 4; e++) {
        const float ns = (s[e] - mean) * rstd * wv[e] + bv[e];
        o[e] = (bf16_t)((float)rv[e] * ns * (float)gv[e]);
    }
    *(bf16x4*)(outp + base) = o;
}

// ---------------------------------------------------------------------------
// LN2: read x2, write normalized bf16
// ---------------------------------------------------------------------------
__global__ void __launch_bounds__(256)
ln2_kernel(const float* __restrict__ x2, const float* __restrict__ w,
           const float* __restrict__ bias, bf16_t* __restrict__ xx2)
{
    const int row = blockIdx.x;
    const int d0 = threadIdx.x * 4;
    const float* xc = x2 + (size_t)row * D_DIM;
    f32x4 c = *(const f32x4*)(xc + d0);
    float sc = 0.f, qc = 0.f;
    #pragma unroll
    for (int e = 0; e < 4; e++) { sc += c[e]; qc += c[e] * c[e]; }
    #pragma unroll
    for (int off = 32; off > 0; off >>= 1) {
        sc += __shfl_down(sc, off); qc += __shfl_down(qc, off);
    }
    __shared__ float red[8];
    const int wv = threadIdx.x >> 6, ln = threadIdx.x & 63;
    if (ln == 0) { red[wv] = sc; red[4 + wv] = qc; }
    __syncthreads();
    sc = red[0] + red[1] + red[2] + red[3];
    qc = red[4] + red[5] + red[6] + red[7];
    const float inv = 1.f / (float)D_DIM;
    const float m = sc * inv, v = qc * inv - m * m, rs = rsqrtf(v + 1e-5f);
    bf16x4 o;
    #pragma unroll
    for (int e = 0; e < 4; e++) {
        const int d = d0 + e;
        o[e] = (bf16_t)((c[e] - m) * rs * w[d] + bias[d]);
    }
    *(bf16x4*)(xx2 + (size_t)row * D_DIM + d0) = o;
}

// ---------------------------------------------------------------------------
// GRN pass 2: gx = sqrt(sum over 8 m-tile partials), nx = gx/(mean_d(gx)+1e-6)
// ---------------------------------------------------------------------------
__global__ void __launch_bounds__(1024)
grn2_kernel(const float* __restrict__ partial, float* __restrict__ nx)
{
    const int b = blockIdx.x, d = threadIdx.x;
    float s = 0.f;
    #pragma unroll
    for (int c = 0; c < 8; c++) s += partial[(size_t)(b * 8 + c) * D_DIM + d];
    const float gx = sqrtf(s);
    float v = gx;
    #pragma unroll
    for (int off = 32; off > 0; off >>= 1) v += __shfl_down(v, off);
    __shared__ float red[16];
    if ((threadIdx.x & 63) == 0) red[threadIdx.x >> 6] = v;
    __syncthreads();
    float tot = 0.f;
    #pragma unroll
    for (int i = 0; i < 16; i++) tot += red[i];
    nx[b * D_DIM + d] = gx / (tot * (1.f / (float)D_DIM) + 1e-6f);
}

// ---------------------------------------------------------------------------
// frh = fr * (gamma*(h*nx) + beta + h) -> bf16
// ---------------------------------------------------------------------------
__global__ void __launch_bounds__(256)
frh_kernel(const float* __restrict__ h, const bf16_t* __restrict__ fr,
           const float* __restrict__ nx, const float* __restrict__ gamma,
           const float* __restrict__ beta, bf16_t* __restrict__ outp)
{
    const size_t gid = (size_t)blockIdx.x * 256 + threadIdx.x;
    const size_t i4 = gid * 4;
    const int d = (int)(i4 & (D_DIM - 1));
    const int b = (int)(i4 >> 21);     // T*D = 2^21
    f32x4 hv = *(const f32x4*)(h + i4);
    bf16x4 fv = *(const bf16x4*)(fr + i4);
    f32x4 nv = *(const f32x4*)(nx + (size_t)b * D_DIM + d);
    f32x4 gm = *(const f32x4*)(gamma + d);
    f32x4 bt = *(const f32x4*)(beta + d);
    bf16x4 o;
    #pragma unroll
    for (int e = 0; e < 4; e++) {
        const float hh = hv[e];
        const float val = gm[e] * (hh * nv[e]) + bt[e] + hh;
        o[e] = (bf16_t)((float)fv[e] * val);
    }
    *(bf16x4*)(outp + i4) = o;
}

// ---------------------------------------------------------------------------
extern "C" void kernel_launch(void* const* d_in, const int* in_sizes, int n_in,
                              void* d_out, int out_size, void* d_ws, size_t ws_size,
                              hipStream_t stream)
{
    (void)in_sizes; (void)n_in; (void)out_size; (void)ws_size;

    const float* x      = (const float*)d_in[0];
    const float* state0 = (const float*)d_in[1];
    const float* ln1_w  = (const float*)d_in[2];
    const float* ln1_b  = (const float*)d_in[3];
    const float* ln2_w  = (const float*)d_in[4];
    const float* ln2_b  = (const float*)d_in[5];
    const float* gn_w   = (const float*)d_in[6];
    const float* gn_b   = (const float*)d_in[7];
    const float* grn_g  = (const float*)d_in[8];
    const float* grn_b  = (const float*)d_in[9];
    const float* decay  = (const float*)d_in[10];
    const float* bfk    = (const float*)d_in[20];
    const float* bfv    = (const float*)d_in[22];
    const float* bfr    = (const float*)d_in[24];

    // workspace layout (~223 MB total)
    const size_t WSZ = (size_t)D_DIM * D_DIM;
    float*  F1 = (float*)d_ws;         // u -> states -> h        (fp32, 64MB)
    bf16_t* B0 = (bf16_t*)(F1 + SZ);   // xm -> xx2               (bf16, 32MB)
    bf16_t* B1 = B0 + SZ;              // mixed -> k_ffn
    bf16_t* B2 = B1 + SZ;              // sr=sigmoid(r) -> fr
    bf16_t* B3 = B2 + SZ;              // g -> frh
    bf16_t* WT = B3 + SZ;              // 11 transposed bf16 weights (22MB)
    float*  carry   = (float*)(WT + NW * WSZ);
    float*  inc     = carry + (size_t)B_DIM * CCH * D_DIM;
    float*  partial = inc + (size_t)B_DIM * CCH * D_DIM;   // 64 x D grn partials
    float*  nxp     = partial + (size_t)64 * D_DIM;
    float*  ewp     = nxp + (size_t)B_DIM * D_DIM;

    // weight slots (fusion-contiguous):
    // 0 Wr, 1 Wg (pair proj), 2 Wk, 3 Wv, 4 Wa, 5 Wb (uv),
    // 6 Wout, 7 Wfk, 8 Wfr (pair ffn), 9 Wfv, 10 Wffnout
    WList wl;
    const int widx[NW] = {11, 14, 12, 13, 15, 16, 17, 19, 23, 21, 18};
    for (int i = 0; i < NW; i++) wl.w[i] = (const float*)d_in[widx[i]];

    float* out_x  = (float*)d_out;
    float* out_st = out_x + SZ;

    transpose_cvt_kernel<<<dim3(32, 32, NW), dim3(32, 8), 0, stream>>>(wl, WT);
    ew_kernel<<<4, 256, 0, stream>>>(decay, ewp);
    ln_shift_kernel<<<M_DIM, 256, 0, stream>>>(x, ln1_w, ln1_b, B0);

    // pair proj (256x128): sr=sigmoid(xm@Wr)->B2, g=sigmoid(xm@Wg)->B3
    gemm_pair_kernel<0><<<512, 512, 0, stream>>>(
        B0, WT + 0 * WSZ, WT + 1 * WSZ, B2, B3, nullptr, nullptr);
    // u = (xm@Wk)*(xm@Wv) + (xm@Wa)*(xm@Wb)  -> F1 (single write)
    gemm_uv_kernel<<<1024, 256, 0, stream>>>(B0, WT + 2 * WSZ, F1);

    scan1_kernel<<<(CCH * B_DIM * D_DIM) / 256, 256, 0, stream>>>(F1, ewp, carry);
    scan2_kernel<<<(B_DIM * D_DIM) / 256, 256, 0, stream>>>(state0, ewp, carry, inc, out_st);
    mixed_kernel<<<M_DIM, 256, 0, stream>>>(F1, inc, ewp, B2, B3, gn_w, gn_b, B1);

    // x2 = x + mixed @ Wout  -> directly into d_out
    gemm2_kernel<8, 3><<<512, 512, 0, stream>>>(
        B1, WT + 6 * WSZ, out_x, nullptr, nullptr, nullptr, x);
    ln2_kernel<<<M_DIM, 256, 0, stream>>>(out_x, ln2_w, ln2_b, B0);

    // pair ffn (256x128): k_ffn = relu^2(xx2@Wfk + bfk)->B1, fr = sigmoid(xx2@Wfr + bfr)->B2
    gemm_pair_kernel<1><<<512, 512, 0, stream>>>(
        B0, WT + 7 * WSZ, WT + 8 * WSZ, B1, B2, bfk, bfr);
    // h = k_ffn @ Wfv + bfv -> F1, plus grn h^2 partials -> partial (MODE 7)
    gemm2_kernel<8, 7><<<512, 512, 0, stream>>>(
        B1, WT + 9 * WSZ, F1, partial, bfv, nullptr, nullptr);

    grn2_kernel<<<B_DIM, 1024, 0, stream>>>(partial, nxp);
    frh_kernel<<<M_DIM, 256, 0, stream>>>(F1, B2, nxp, grn_g, grn_b, B3);

    // out = x2 + frh @ Wffnout  (in-place accumulate into d_out)
    gemm2_kernel<8, 3><<<512, 512, 0, stream>>>(
        B3, WT + 10 * WSZ, out_x, nullptr, nullptr, nullptr, out_x);
}